// Round 11
// baseline (490.858 us; speedup 1.0000x reference)
//
#include <hip/hip_runtime.h>

typedef __attribute__((ext_vector_type(8))) short bf16x8;
typedef __attribute__((ext_vector_type(4))) float f32x4;

// ---------------- problem constants ----------------
constexpr int kB   = 2;
constexpr int kN   = 4096;   // tokens (64x64)
constexpr int kC   = 320;    // channels
constexpr int kNA  = 3072;   // src (non-dst) tokens
constexpr int kNB  = 1024;   // dst tokens
constexpr int kNM  = 2048;   // merged seq len
constexpr int kR   = 2048;   // merged src count
constexpr int kH   = 8;
constexpr int kDH  = 40;
constexpr int kLC  = 77;
constexpr int kDC  = 768;
constexpr int kDFF = 1280;

__device__ __forceinline__ unsigned short f2b(float f){
  unsigned u = __float_as_uint(f);
  u += 0x7FFF + ((u>>16)&1);
  return (unsigned short)(u>>16);
}
__device__ __forceinline__ float b2f(unsigned short h){ return __uint_as_float(((unsigned)h)<<16); }

__device__ __forceinline__ float wave_sum(float v){
  #pragma unroll
  for (int m=32;m>=1;m>>=1) v += __shfl_xor(v, m, 64);
  return v;
}
__device__ __forceinline__ int d_arank(int h, int w){
  int base = 32*((h+1)>>1) + 64*(h>>1);
  return base + ((h&1) ? w : (w>>1));
}

// ---------------- ws layout (byte offsets) ----------------
constexpr size_t rndB(size_t x){ return (x + 255) & ~(size_t)255; }
constexpr size_t B_mnA  = 0;                                             // fp32 [2*3072*320]
constexpr size_t B_mnB  = rndB(B_mnA + (size_t)kB*kNA*kC*4);             // fp32 [2*1024*320]
constexpr size_t B_y32  = rndB(B_mnB + (size_t)kB*kNB*kC*4);             // fp32 [2*4096*320] (LN1)
constexpr size_t B_xm   = rndB(B_y32 + (size_t)kB*kN*kC*4);              // fp32 [2*2048*320]
constexpr size_t B_xo1  = rndB(B_xm  + (size_t)kB*kNM*kC*4);             // fp32 [2*2048*320]
constexpr size_t B_net1 = rndB(B_xo1 + (size_t)kB*kNM*kC*4);             // fp32 [2*4096*320]
constexpr size_t B_H    = 0;  // bf16 [8192*2560] overlays mnA..net1 (41.94 MB, all dead by then)
constexpr size_t B_net2 = rndB(B_net1 + (size_t)kB*kN*kC*4);             // fp32 [2*4096*320]
constexpr size_t B_G    = rndB(B_net2 + (size_t)kB*kN*kC*4);             // bf16 [8192*1280]
constexpr size_t B_QKb  = rndB(B_G    + (size_t)kB*kN*kDFF*2);           // bf16 [4096*640] (Q|K)
constexpr size_t B_Vtg  = rndB(B_QKb  + (size_t)kB*kNM*640*2);           // bf16 [320*4096] (V^T)
constexpr size_t B_yb   = rndB(B_Vtg  + (size_t)320*kB*kNM*2);           // bf16 [8192*320]
constexpr size_t B_xmb  = rndB(B_yb   + (size_t)kB*kN*kC*2);             // bf16 [4096*320]
constexpr size_t B_Ao1b = rndB(B_xmb  + (size_t)kB*kNM*kC*2);            // bf16 [4096*320]
constexpr size_t B_Q2b  = rndB(B_Ao1b + (size_t)kB*kNM*kC*2);            // bf16 [8192*320]
constexpr size_t B_Ao2b = rndB(B_Q2b  + (size_t)kB*kN*kC*2);             // bf16 [8192*320]
constexpr size_t B_KV2b = rndB(B_Ao2b + (size_t)kB*kN*kC*2);             // bf16 [154*640]
constexpr size_t B_Vt2g = rndB(B_KV2b + (size_t)kB*kLC*640*2);           // bf16 [2*320*80] (V2^T pad)
constexpr size_t B_ctxb = rndB(B_Vt2g + (size_t)kB*320*80*2);            // bf16 [154*768]
constexpr size_t B_Wqkv = rndB(B_ctxb + (size_t)kB*kLC*kDC*2);           // bf16 [960*320]
constexpr size_t B_Wo1  = rndB(B_Wqkv + (size_t)960*320*2);              // bf16 [320*320]
constexpr size_t B_Wq2  = rndB(B_Wo1  + (size_t)320*320*2);
constexpr size_t B_Wkv2 = rndB(B_Wq2  + (size_t)320*320*2);              // bf16 [640*768]
constexpr size_t B_Wo2  = rndB(B_Wkv2 + (size_t)640*768*2);
constexpr size_t B_Wff1 = rndB(B_Wo2  + (size_t)320*320*2);              // bf16 [2560*320]
constexpr size_t B_Wff2 = rndB(B_Wff1 + (size_t)2560*320*2);             // bf16 [320*1280]
constexpr size_t B_cnt  = rndB(B_Wff2 + (size_t)320*1280*2);             // fp32 [2*1024]
constexpr size_t B_pack = rndB(B_cnt  + (size_t)kB*kNB*4);               // u64 [2*3072]
constexpr size_t B_rank = rndB(B_pack + (size_t)kB*kNA*8);               // int [2*3072]
constexpr size_t B_nidx = rndB(B_rank + (size_t)kB*kNA*4);
constexpr size_t B_mrg  = rndB(B_nidx + (size_t)kB*kNA*4);
constexpr size_t B_slot = rndB(B_mrg  + (size_t)kB*kNA*4);
constexpr size_t B_unml = rndB(B_slot + (size_t)kB*kNA*4);
constexpr size_t B_ucnt = rndB(B_unml + (size_t)kB*kNB*4);
constexpr size_t B_aidx = rndB(B_ucnt + 64);
constexpr size_t B_Op   = rndB(B_aidx + (size_t)kNA*4);                  // fp32 [2][4096*320] partial O
constexpr size_t B_lp   = rndB(B_Op   + (size_t)2*4096*320*4);           // fp32 [2][4096*8] partial l

// ---------------- gather + (idx/init/rank-zero absorbed) ----------------
__global__ void k_gather(const float* __restrict__ net, float* __restrict__ mA, float* __restrict__ mB,
                         unsigned long long* __restrict__ pack, int* __restrict__ ucnt,
                         int* __restrict__ a_idx, int* __restrict__ rank){
  int blk = blockIdx.x; int b = blk >> 12; int t = blk & 4095;
  int lane = threadIdx.x;
  int gid = blk*64 + lane;
  if (gid < kB*kNA){ pack[gid] = 0ull; rank[gid] = 0; }
  if (gid < kB) ucnt[gid] = 0;
  if (gid < kN){
    int h = gid>>6, w = gid&63;
    if ((h|w)&1) a_idx[d_arank(h,w)] = gid;
  }
  const float* xp = net + ((size_t)b*kN + t)*kC;
  float v[5]; float s2 = 0.f;
  #pragma unroll
  for (int i=0;i<5;i++){ float f = xp[lane + i*64]; v[i]=f; s2 += f*f; }
  s2 = wave_sum(s2);
  float rn = 1.0f / sqrtf(s2);
  int h=t>>6, w=t&63;
  float* dp;
  if (!((h|w)&1)) dp = mB + ((size_t)b*kNB + ((h>>1)*32+(w>>1)))*kC;
  else            dp = mA + ((size_t)b*kNA + d_arank(h,w))*kC;
  #pragma unroll
  for (int i=0;i<5;i++) dp[lane + i*64] = v[i]*rn;
}

// ---------------- fused score GEMM (NT, exact fp32, 128x64 tile, 8x4 microtile) + row argmax ----------------
__global__ __launch_bounds__(256) void k_scores(const float* __restrict__ mA, const float* __restrict__ mB,
                                                unsigned long long* __restrict__ pack){
  __shared__ __align__(16) float As[16][136];   // [k][m 0..127]
  __shared__ __align__(16) float Bs[16][68];    // [k][n 0..63]
  const int b = blockIdx.z;
  const int m0 = blockIdx.x*128, n0 = blockIdx.y*64;
  const int tid = threadIdx.x;
  const int mr = tid>>4, nc = tid&15;           // rows m0+mr*8.., cols n0+nc*4..
  const float* Ab = mA + (size_t)b*kNA*kC;
  const float* Bb = mB + (size_t)b*kNB*kC;
  float acc[8][4] = {};
  const int ar = tid>>1, ac8 = (tid&1)*8;       // A staging: row, col-octet
  const int br = tid>>2, bc4 = (tid&3)*4;       // B staging
  for (int k0=0; k0<kC; k0+=16){
    __syncthreads();
    {
      float4 a0 = *reinterpret_cast<const float4*>(&Ab[(size_t)(m0+ar)*kC + k0 + ac8]);
      float4 a1 = *reinterpret_cast<const float4*>(&Ab[(size_t)(m0+ar)*kC + k0 + ac8 + 4]);
      As[ac8+0][ar]=a0.x; As[ac8+1][ar]=a0.y; As[ac8+2][ar]=a0.z; As[ac8+3][ar]=a0.w;
      As[ac8+4][ar]=a1.x; As[ac8+5][ar]=a1.y; As[ac8+6][ar]=a1.z; As[ac8+7][ar]=a1.w;
      float4 bv = *reinterpret_cast<const float4*>(&Bb[(size_t)(n0+br)*kC + k0 + bc4]);
      Bs[bc4+0][br]=bv.x; Bs[bc4+1][br]=bv.y; Bs[bc4+2][br]=bv.z; Bs[bc4+3][br]=bv.w;
    }
    __syncthreads();
    #pragma unroll
    for (int kk=0;kk<16;kk++){
      const float4 a4a = *reinterpret_cast<const float4*>(&As[kk][mr*8]);
      const float4 a4b = *reinterpret_cast<const float4*>(&As[kk][mr*8+4]);
      const float4 b4  = *reinterpret_cast<const float4*>(&Bs[kk][nc*4]);
      const float aa[8]={a4a.x,a4a.y,a4a.z,a4a.w,a4b.x,a4b.y,a4b.z,a4b.w};
      const float bb[4]={b4.x,b4.y,b4.z,b4.w};
      #pragma unroll
      for (int i=0;i<8;i++)
        #pragma unroll
        for (int j=0;j<4;j++)
          acc[i][j] = fmaf(aa[i], bb[j], acc[i][j]);
    }
  }
  #pragma unroll
  for (int i=0;i<8;i++){
    float bs = acc[i][0]; int bj = n0 + nc*4;
    #pragma unroll
    for (int j=1;j<4;j++){
      float v = acc[i][j];
      if (v > bs){ bs=v; bj=n0+nc*4+j; }
    }
    #pragma unroll
    for (int off=1; off<16; off<<=1){
      float os = __shfl_xor(bs, off, 16);
      int   oj = __shfl_xor(bj, off, 16);
      if (os > bs || (os == bs && oj < bj)){ bs=os; bj=oj; }
    }
    if (nc == 0){
      unsigned int u = __float_as_uint(bs);
      unsigned int key = (u & 0x80000000u) ? ~u : (u | 0x80000000u);
      unsigned long long pk = ((unsigned long long)key << 32) |
                              (unsigned long long)(0xFFFFFFFFu - (unsigned int)bj);
      atomicMax(&pack[(size_t)b*kNA + m0 + mr*8 + i], pk);
    }
  }
}
// partial rank over a 256-key j-chunk (grid: 12 i-blocks x 12 j-chunks x 2 batches)
__global__ __launch_bounds__(256) void k_rank_part(const unsigned long long* __restrict__ pack,
                                                   int* __restrict__ rank){
  __shared__ unsigned int keys[256];
  const int b = blockIdx.z;
  const int i = blockIdx.x*256 + threadIdx.x;
  const int j0 = blockIdx.y*256;
  const unsigned long long* pb = pack + (size_t)b*kNA;
  keys[threadIdx.x] = (unsigned int)(pb[j0 + threadIdx.x]>>32);
  unsigned int ki = (unsigned int)(pb[i]>>32);
  __syncthreads();
  int cnt = 0;
  #pragma unroll 8
  for (int jj=0;jj<256;jj++){
    unsigned int kj = keys[jj];
    int j = j0 + jj;
    cnt += (kj > ki) || (kj == ki && j < i);
  }
  atomicAdd(&rank[(size_t)b*kNA + i], cnt);
}
// decode node_idx + merged/slot assignment from accumulated rank
__global__ void k_rank_assign(const unsigned long long* __restrict__ pack, const int* __restrict__ rank,
                              int* __restrict__ node_idx, int* __restrict__ merged,
                              int* __restrict__ slot_of, int* __restrict__ unm_list,
                              int* __restrict__ ucnt){
  int b = blockIdx.y;
  int i = blockIdx.x*256 + threadIdx.x;
  unsigned long long p = pack[(size_t)b*kNA + i];
  node_idx[(size_t)b*kNA + i] = (int)(0xFFFFFFFFu - (unsigned int)(p & 0xFFFFFFFFull));
  int mg = rank[(size_t)b*kNA + i] < kR;
  merged[(size_t)b*kNA + i] = mg;
  if (!mg){
    int s = atomicAdd(&ucnt[b], 1);
    unm_list[(size_t)b*kNB + s] = i;
    slot_of[(size_t)b*kNA + i] = s;
  }
}

// ---------------- layernorm (OB: bf16 out) ----------------
template<bool OB>
__global__ void k_ln(const float* __restrict__ x, const float* __restrict__ g,
                     const float* __restrict__ be, void* __restrict__ yv){
  const int row = blockIdx.x;
  const int lane = threadIdx.x;
  const float* xp = x + (size_t)row*kC;
  float v[5]; float s=0.f, s2=0.f;
  #pragma unroll
  for (int i=0;i<5;i++){ float f = xp[lane + i*64]; v[i]=f; s+=f; s2+=f*f; }
  s = wave_sum(s); s2 = wave_sum(s2);
  float mu = s * (1.0f/kC);
  float var = s2 * (1.0f/kC) - mu*mu;
  float rstd = rsqrtf(var + 1e-5f);
  #pragma unroll
  for (int i=0;i<5;i++){
    int c = lane + i*64;
    float o = (v[i]-mu)*rstd*g[c] + be[c];
    if (OB) ((unsigned short*)yv)[(size_t)row*kC + c] = f2b(o);
    else    ((float*)yv)[(size_t)row*kC + c] = o;
  }
}

// ---------------- merge (unm + dst fused; src; scale) ----------------
__global__ void k_merge_ud(const float* __restrict__ y, const int* __restrict__ a_idx,
                           const int* __restrict__ unm_list, unsigned short* __restrict__ xmb,
                           float* __restrict__ xm, float* __restrict__ cnt){
  int blk = blockIdx.x;
  int lane = threadIdx.x;
  if (blk < kB*kNB){
    int b = blk >> 10; int s = blk & 1023;
    int i = unm_list[(size_t)b*kNB + s];
    int t = a_idx[i];
    const float* sp = y + ((size_t)b*kN + t)*kC;
    unsigned short* dp = xmb + ((size_t)b*kNM + s)*kC;
    #pragma unroll
    for (int q=0;q<5;q++) dp[lane+q*64] = f2b(sp[lane+q*64]);
  } else {
    blk -= kB*kNB;
    int b = blk >> 10; int j = blk & 1023;
    int t = 128*(j>>5) + 2*(j&31);
    const float* sp = y + ((size_t)b*kN + t)*kC;
    float* dp = xm + ((size_t)b*kNM + kNB + j)*kC;
    #pragma unroll
    for (int q=0;q<5;q++) dp[lane+q*64] = sp[lane+q*64];
    if (lane==0) cnt[(size_t)b*kNB + j] = 1.0f;
  }
}
__global__ void k_merge_src(const float* __restrict__ y, const int* __restrict__ a_idx,
                            const int* __restrict__ merged, const int* __restrict__ node_idx,
                            float* __restrict__ xm, float* __restrict__ cnt){
  int blk = blockIdx.x; int b = blk / kNA; int i = blk % kNA;
  if (!merged[(size_t)b*kNA + i]) return;
  int t = a_idx[i]; int j = node_idx[(size_t)b*kNA + i];
  const float* sp = y + ((size_t)b*kN + t)*kC;
  float* dp = xm + ((size_t)b*kNM + kNB + j)*kC;
  int lane = threadIdx.x;
  #pragma unroll
  for (int q=0;q<5;q++) atomicAdd(&dp[lane+q*64], sp[lane+q*64]);
  if (lane==0) atomicAdd(&cnt[(size_t)b*kNB + j], 1.0f);
}
__global__ void k_merge_scale(const float* __restrict__ xm, const float* __restrict__ cnt,
                              unsigned short* __restrict__ xmb){
  int blk = blockIdx.x; int b = blk >> 10; int j = blk & 1023;
  float inv = 1.0f / cnt[(size_t)b*kNB + j];
  const float* sp = xm + ((size_t)b*kNM + kNB + j)*kC;
  unsigned short* dp = xmb + ((size_t)b*kNM + kNB + j)*kC;
  int lane = threadIdx.x;
  #pragma unroll
  for (int q=0;q<5;q++) dp[lane+q*64] = f2b(sp[lane+q*64]*inv);
}

// ---------------- batched weight transpose+convert + ctx convert + Vt2 pad zero ----------------
__global__ __launch_bounds__(256) void k_wt_all(
    const float* __restrict__ w0, const float* __restrict__ w1, const float* __restrict__ w2,
    const float* __restrict__ w3, const float* __restrict__ w4, const float* __restrict__ w5,
    const float* __restrict__ w6, const float* __restrict__ w7, const float* __restrict__ w8,
    const float* __restrict__ w9,
    unsigned short* __restrict__ Wqkv, unsigned short* __restrict__ Wo1,
    unsigned short* __restrict__ Wq2,  unsigned short* __restrict__ Wkv2,
    unsigned short* __restrict__ Wo2,  unsigned short* __restrict__ Wff1,
    unsigned short* __restrict__ Wff2,
    const float* __restrict__ ctx, unsigned short* __restrict__ ctxb,
    unsigned short* __restrict__ Vt2){
  const int bid = blockIdx.x;
  const int tid = threadIdx.x;
  if (bid >= 570){
    int base = (bid-570)*2048 + tid*8;
    #pragma unroll
    for (int j=0;j<8;j++){
      int i = base + j;
      if (i < kB*kLC*kDC) ctxb[i] = f2b(ctx[i]);
    }
    if (bid == 570){
      for (int r=tid; r<kB*320; r+=256){
        Vt2[(size_t)r*80 + 77] = 0; Vt2[(size_t)r*80 + 78] = 0; Vt2[(size_t)r*80 + 79] = 0;
      }
    }
    return;
  }
  const int jb[11]   = {0,25,50,75,100,125,185,245,270,470,570};
  const float* srcs[10] = {w0,w1,w2,w3,w4,w5,w6,w7,w8,w9};
  unsigned short* dsts[10] = {Wqkv, Wqkv+320*320, Wqkv+640*320, Wo1, Wq2,
                              Wkv2, Wkv2+320*768, Wo2, Wff1, Wff2};
  const int Kd[10] = {320,320,320,320,320,768,768,320,320,1280};
  const int Nd[10] = {320,320,320,320,320,320,320,320,2560,320};
  int job = 0;
  while (bid >= jb[job+1]) job++;
  int local = bid - jb[job];
  const int Nt = (Nd[job]+63)>>6;
  int k0 = (local / Nt)*64, n0 = (local % Nt)*64;
  const float* W = srcs[job];
  unsigned short* Wt = dsts[job];
  const int K = Kd[job], N = Nd[job];
  __shared__ float tile[64][65];
  #pragma unroll
  for (int l=0;l<16;l++){
    int e = tid + l*256; int r = e>>6, c = e&63;
    int gk = k0+r, gn = n0+c;
    tile[r][c] = (gk<K && gn<N) ? W[(size_t)gk*N+gn] : 0.f;
  }
  __syncthreads();
  #pragma unroll
  for (int l=0;l<16;l++){
    int e = tid + l*256; int r = e>>6, c = e&63;
    int gn = n0+r, gk = k0+c;
    if (gn<N && gk<K) Wt[(size_t)gn*K+gk] = f2b(tile[c][r]);
  }
}

// ---------------- bf16 MFMA GEMM 128x128: out = A @ Bt^T (+bias)(+resid) ----------------
template<typename OT, bool BIAS, bool RES, int SVM>
__global__ __launch_bounds__(256) void k_bgemm(const unsigned short* __restrict__ A,
    const unsigned short* __restrict__ Bt, const float* __restrict__ bias,
    const float* __restrict__ resid, OT* __restrict__ out, unsigned short* __restrict__ vt,
    int M, int N, int K, int ldo){
  constexpr int LDK = 72;
  __shared__ unsigned short As[128*LDK];
  __shared__ unsigned short Bs[128*LDK];
  const int tid = threadIdx.x;
  const int m0 = blockIdx.x*128, n0 = blockIdx.y*128;
  const int wid = tid>>6, lane = tid&63;
  const int wm = (wid>>1)*64, wn = (wid&1)*64;
  const int lr = lane&15, quad = lane>>4;
  const f32x4 zero4 = {0.f,0.f,0.f,0.f};
  f32x4 acc[4][4];
  #pragma unroll
  for (int i=0;i<4;i++)
    #pragma unroll
    for (int j=0;j<4;j++) acc[i][j] = zero4;
  for (int k0=0; k0<K; k0+=64){
    __syncthreads();
    #pragma unroll
    for (int l=0;l<4;l++){
      int e = tid + l*256;
      int row = e>>3, seg = (e&7)*8;
      int gm = m0+row;
      uint4 va = (gm<M) ? *reinterpret_cast<const uint4*>(&A[(size_t)gm*K + k0 + seg])
                        : make_uint4(0u,0u,0u,0u);
      *reinterpret_cast<uint4*>(&As[row*LDK + seg]) = va;
      int gn = n0+row;
      uint4 vb = (gn<N) ? *reinterpret_cast<const uint4*>(&Bt[(size_t)gn*K + k0 + seg])
                        : make_uint4(0u,0u,0u,0u);
      *reinterpret_cast<uint4*>(&Bs[row*LDK + seg]) = vb;
    }
    __syncthreads();
    #pragma unroll
    for (int kk=0; kk<64; kk+=32){
      bf16x8 af[4], bfr[4];
      #pragma unroll
      for (int i=0;i<4;i++) af[i]  = *reinterpret_cast<const bf16x8*>(&As[(wm+i*16+lr)*LDK + kk + quad*8]);
      #pragma unroll
      for (int j=0;j<4;j++) bfr[j] = *reinterpret_cast<const bf16x8*>(&Bs[(wn+j*16+lr)*LDK + kk + quad*8]);
      #pragma unroll
      for (int i=0;i<4;i++)
        #pragma unroll
        for (int j=0;j<4;j++)
          acc[i][j] = __builtin_amdgcn_mfma_f32_16x16x32_bf16(af[i], bfr[j], acc[i][j], 0, 0, 0);
    }
  }
  #pragma unroll
  for (int i=0;i<4;i++){
    #pragma unroll
    for (int j=0;j<4;j++){
      int gn = n0 + wn + j*16 + lr;
      if (gn >= N) continue;
      float bv = BIAS ? bias[gn] : 0.f;
      #pragma unroll
      for (int r=0;r<4;r++){
        int gm = m0 + wm + i*16 + quad*4 + r;
        if (gm >= M) continue;
        float v = acc[i][j][r] + bv;
        if (RES) v += resid[(size_t)gm*ldo + gn];
        if (SVM == 1 && gn >= 640){
          vt[(size_t)(gn-640)*4096 + gm] = f2b(v);
        } else if (SVM == 2 && gn >= 320){
          int bb = gm / 77, tok = gm - bb*77;
          vt[((size_t)bb*320 + (gn-320))*80 + tok] = f2b(v);
        } else {
          if constexpr (sizeof(OT)==2) out[(size_t)gm*ldo + gn] = (OT)f2b(v);
          else                         out[(size_t)gm*ldo + gn] = (OT)v;
        }
      }
    }
  }
}

// ---------------- bf16 MFMA GEMM 64x64 tile (high-occupancy, for narrow-N GEMMs) ----------------
template<typename OT, bool BIAS, bool RES, int SVM>
__global__ __launch_bounds__(256) void k_bgemm64(const unsigned short* __restrict__ A,
    const unsigned short* __restrict__ Bt, const float* __restrict__ bias,
    const float* __restrict__ resid, OT* __restrict__ out, unsigned short* __restrict__ vt,
    int M, int N, int K, int ldo){
  constexpr int LDK = 72;
  __shared__ unsigned short As[64*LDK];
  __shared__ unsigned short Bs[64*LDK];
  const int tid = threadIdx.x;
  const int m0 = blockIdx.x*64, n0 = blockIdx.y*64;
  const int wid = tid>>6, lane = tid&63;
  const int wm = (wid>>1)*32, wn = (wid&1)*32;
  const int lr = lane&15, quad = lane>>4;
  const f32x4 zero4 = {0.f,0.f,0.f,0.f};
  f32x4 acc[2][2];
  #pragma unroll
  for (int i=0;i<2;i++)
    #pragma unroll
    for (int j=0;j<2;j++) acc[i][j] = zero4;
  for (int k0=0; k0<K; k0+=64){
    __syncthreads();
    #pragma unroll
    for (int l=0;l<2;l++){
      int e = tid + l*256;
      int row = e>>3, seg = (e&7)*8;
      int gm = m0+row;
      uint4 va = (gm<M) ? *reinterpret_cast<const uint4*>(&A[(size_t)gm*K + k0 + seg])
                        : make_uint4(0u,0u,0u,0u);
      *reinterpret_cast<uint4*>(&As[row*LDK + seg]) = va;
      int gn = n0+row;
      uint4 vb = (gn<N) ? *reinterpret_cast<const uint4*>(&Bt[(size_t)gn*K + k0 + seg])
                        : make_uint4(0u,0u,0u,0u);
      *reinterpret_cast<uint4*>(&Bs[row*LDK + seg]) = vb;
    }
    __syncthreads();
    #pragma unroll
    for (int kk=0; kk<64; kk+=32){
      bf16x8 af[2], bfr[2];
      #pragma unroll
      for (int i=0;i<2;i++) af[i]  = *reinterpret_cast<const bf16x8*>(&As[(wm+i*16+lr)*LDK + kk + quad*8]);
      #pragma unroll
      for (int j=0;j<2;j++) bfr[j] = *reinterpret_cast<const bf16x8*>(&Bs[(wn+j*16+lr)*LDK + kk + quad*8]);
      #pragma unroll
      for (int i=0;i<2;i++)
        #pragma unroll
        for (int j=0;j<2;j++)
          acc[i][j] = __builtin_amdgcn_mfma_f32_16x16x32_bf16(af[i], bfr[j], acc[i][j], 0, 0, 0);
    }
  }
  #pragma unroll
  for (int i=0;i<2;i++){
    #pragma unroll
    for (int j=0;j<2;j++){
      int gn = n0 + wn + j*16 + lr;
      if (gn >= N) continue;
      float bv = BIAS ? bias[gn] : 0.f;
      #pragma unroll
      for (int r=0;r<4;r++){
        int gm = m0 + wm + i*16 + quad*4 + r;
        if (gm >= M) continue;
        float v = acc[i][j][r] + bv;
        if (RES) v += resid[(size_t)gm*ldo + gn];
        if (SVM == 1 && gn >= 640){
          vt[(size_t)(gn-640)*4096 + gm] = f2b(v);
        } else if (SVM == 2 && gn >= 320){
          int bb = gm / 77, tok = gm - bb*77;
          vt[((size_t)bb*320 + (gn-320))*80 + tok] = f2b(v);
        } else {
          if constexpr (sizeof(OT)==2) out[(size_t)gm*ldo + gn] = (OT)f2b(v);
          else                         out[(size_t)gm*ldo + gn] = (OT)v;
        }
      }
    }
  }
}

// ---------------- GEGLU elementwise: G = H[:, :1280] * gelu(H[:, 1280:]) ----------------
__global__ void k_geglu(const unsigned short* __restrict__ H, unsigned short* __restrict__ G){
  int e = blockIdx.x*256 + threadIdx.x;   // 8192*160 threads
  int m = e/160, t = e - m*160;
  const unsigned short* hp = H + (size_t)m*2560 + t*8;
  uint4 xv = *reinterpret_cast<const uint4*>(hp);
  uint4 gv = *reinterpret_cast<const uint4*>(hp + 1280);
  const unsigned short* xu = reinterpret_cast<const unsigned short*>(&xv);
  const unsigned short* gu = reinterpret_cast<const unsigned short*>(&gv);
  unsigned short ov[8];
  #pragma unroll
  for (int d=0; d<8; d++){
    float x = b2f(xu[d]);
    float g = b2f(gu[d]);
    float ge = 0.5f*g*(1.0f + erff(g*0.70710678118654752f));
    ov[d] = f2b(x*ge);
  }
  *reinterpret_cast<uint4*>(G + (size_t)m*1280 + t*8) = *reinterpret_cast<const uint4*>(ov);
}

// ---------------- MFMA flash self-attn (split-key x2, reg-Q, shift-free softmax) ----------------
// blockIdx.x = qtile*2 + kz. Emits unnormalized partial O (fp32) + partial l per (kz).
__global__ __launch_bounds__(256) void k_attn1(const unsigned short* __restrict__ QK,
                                               const unsigned short* __restrict__ Vtg,
                                               float* __restrict__ Opart,
                                               float* __restrict__ lpart){
  constexpr int LP = 72, LV = 136;
  __shared__ unsigned short Ks[128*LP];   // [key][d pad64]
  __shared__ unsigned short Vt[48*LV];    // [d pad48][key 128 pad136]
  __shared__ unsigned short Ps[64*LV];    // [q][key 128 pad136]
  const int b = blockIdx.z, hh = blockIdx.y;
  const int bx = blockIdx.x;
  const int q0 = (bx>>1)*64, kz = bx&1;
  const int tid = threadIdx.x;
  const int wid = tid>>6, lane = tid&63;
  const int lr = lane&15, quad = lane>>4;
  const int wm = wid*16;
  const float scale = 0.15811388300841898f; // 1/sqrt(40)
  const unsigned short* Kb = QK + ((size_t)b*kNM)*640 + 320 + hh*kDH;
  const unsigned short* Vb = Vtg + (size_t)hh*kDH*4096 + (size_t)b*kNM;
  const uint4 z4 = make_uint4(0u,0u,0u,0u);
  // Q fragments: direct per-lane 16B global loads (A-layout). Cols 40.. are pad -> zero.
  const unsigned short* Qrow = QK + ((size_t)b*kNM + q0 + wm + lr)*640 + hh*kDH;
  bf16x8 aq0 = *reinterpret_cast<const bf16x8*>(Qrow + quad*8);
  bf16x8 aq1 = {0,0,0,0,0,0,0,0};
  if (quad == 0) aq1 = *reinterpret_cast<const bf16x8*>(Qrow + 32);
  // zero pads: Ks cols 40..63 (128 x 3 segs), Vt rows 40..47 (8 x 17 segs)
  for (int e=tid; e<384; e+=256){
    int row=e/3, seg=40+(e%3)*8;
    *reinterpret_cast<uint4*>(&Ks[row*LP+seg]) = z4;
  }
  for (int e=tid; e<136; e+=256){
    int row=40+e/17, seg=(e%17)*8;
    *reinterpret_cast<uint4*>(&Vt[row*LV+seg]) = z4;
  }
  const f32x4 zf = {0.f,0.f,0.f,0.f};
  f32x4 oacc[3] = {zf, zf, zf};
  float l_i[4] = {0.f, 0.f, 0.f, 0.f};
  const int kbeg = kz*1024, kend = kbeg + 1024;
  for (int kt=kbeg; kt<kend; kt+=128){
    __syncthreads();
    for (int e=tid; e<640; e+=256){          // K: 128 rows x 5 segs
      int row=e/5, seg=(e%5)*8;
      *reinterpret_cast<uint4*>(&Ks[row*LP+seg]) =
        *reinterpret_cast<const uint4*>(Kb + (size_t)(kt+row)*640 + seg);
    }
    for (int e=tid; e<640; e+=256){          // Vt: 40 d-rows x 16 segs (128 tokens)
      int d=e>>4, seg=(e&15)*8;
      *reinterpret_cast<uint4*>(&Vt[d*LV+seg]) =
        *reinterpret_cast<const uint4*>(Vb + (size_t)d*4096 + kt + seg);
    }
    __syncthreads();
    f32x4 sacc[8];
    #pragma unroll
    for (int j=0;j<8;j++){
      bf16x8 bk0 = *reinterpret_cast<const bf16x8*>(&Ks[(j*16+lr)*LP + quad*8]);
      sacc[j] = __builtin_amdgcn_mfma_f32_16x16x32_bf16(aq0, bk0, zf, 0,0,0);
      bf16x8 bk1 = *reinterpret_cast<const bf16x8*>(&Ks[(j*16+lr)*LP + 32 + quad*8]);
      sacc[j] = __builtin_amdgcn_mfma_f32_16x16x32_bf16(aq1, bk1, sacc[j], 0,0,0);
    }
    #pragma unroll
    for (int r=0;r<4;r++){
      int row = wm + quad*4 + r;
      float psum = 0.f;
      #pragma unroll
      for (int j=0;j<8;j++){
        float p = __expf(sacc[j][r]*scale);
        psum += p;
        Ps[row*LV + j*16 + lr] = f2b(p);
      }
      #pragma unroll
      for (int off=1; off<16; off<<=1) psum += __shfl_xor(psum, off, 64);
      l_i[r] += psum;
    }
    #pragma unroll
    for (int s=0;s<4;s++){
      bf16x8 ap = *reinterpret_cast<const bf16x8*>(&Ps[(wm+lr)*LV + s*32 + quad*8]);
      #pragma unroll
      for (int nt=0;nt<3;nt++){
        bf16x8 bv = *reinterpret_cast<const bf16x8*>(&Vt[(nt*16+lr)*LV + s*32 + quad*8]);
        oacc[nt] = __builtin_amdgcn_mfma_f32_16x16x32_bf16(ap, bv, oacc[nt], 0,0,0);
      }
    }
  }
  // emit unnormalized partials
  float* Op = Opart + (size_t)kz*4096*320;
  float* lp = lpart + (size_t)kz*4096*8;
  #pragma unroll
  for (int r=0;r<4;r++){
    int grow = b*kNM + q0 + wm + quad*4 + r;
    #pragma unroll
    for (int nt=0;nt<3;nt++){
      int d = nt*16 + lr;
      if (d < kDH) Op[(size_t)grow*320 + hh*kDH + d] = oacc[nt][r];
    }
    if (lr == 0) lp[(size_t)grow*8 + hh] = l_i[r];
  }
}

// combine split-key partials: Ao1 = (O0+O1)/(l0+l1), bf16 out
__global__ void k_acomb(const float* __restrict__ Opart, const float* __restrict__ lpart,
                        unsigned short* __restrict__ Ao1b){
  int row = blockIdx.x;
  int lane = threadIdx.x;
  const float* o0 = Opart + (size_t)row*320;
  const float* o1 = Opart + (size_t)2*4096*320/2 + (size_t)row*320; // kz=1 slab
  const float* l0 = lpart + (size_t)row*8;
  const float* l1 = lpart + (size_t)4096*8 + (size_t)row*8;
  #pragma unroll
  for (int i=0;i<5;i++){
    int c = lane + i*64;
    int h = c/kDH;
    float v = (o0[c] + o1[c]) / (l0[h] + l1[h]);
    Ao1b[(size_t)row*320 + c] = f2b(v);
  }
}

// ---------------- MFMA one-shot cross-attn: 64 q/block, 77 keys pad 80 ----------------
__global__ __launch_bounds__(256) void k_attn2m(const unsigned short* __restrict__ Q,
                                                const unsigned short* __restrict__ KV,
                                                const unsigned short* __restrict__ Vt2,
                                                unsigned short* __restrict__ Oa){
  constexpr int LP = 72, LP2 = 104;
  __shared__ unsigned short Qs[64*LP];    // [q][d pad64]
  __shared__ unsigned short Ks[80*LP];    // [key pad80][d pad64]
  __shared__ unsigned short Vts[48*LP2];  // [d pad48][key pad96]
  __shared__ unsigned short Ps[64*LP2];   // [q][key pad96]
  const int b = blockIdx.z, hh = blockIdx.y;
  const int q0 = blockIdx.x*64;
  const int tid = threadIdx.x;
  const int wid = tid>>6, lane = tid&63;
  const int lr = lane&15, quad = lane>>4;
  const int wm = wid*16;
  const float scale = 0.15811388300841898f;
  const uint4 z4 = make_uint4(0u,0u,0u,0u);
  for (int e=tid; e<576; e+=256) *reinterpret_cast<uint4*>(&Qs[e*8]) = z4;   // 64*72/8
  for (int e=tid; e<720; e+=256) *reinterpret_cast<uint4*>(&Ks[e*8]) = z4;   // 80*72/8
  for (int e=tid; e<624; e+=256) *reinterpret_cast<uint4*>(&Vts[e*8]) = z4;  // 48*104/8
  for (int e=tid; e<832; e+=256) *reinterpret_cast<uint4*>(&Ps[e*8]) = z4;   // 64*104/8
  __syncthreads();
  for (int e=tid; e<320; e+=256){               // Q: 64 rows x 5 seg
    int row=e/5, seg=(e%5)*8;
    *reinterpret_cast<uint4*>(&Qs[row*LP+seg]) =
      *reinterpret_cast<const uint4*>(Q + ((size_t)b*kN + q0 + row)*kC + hh*kDH + seg);
  }
  for (int e=tid; e<385; e+=256){               // K: 77 rows x 5 seg
    int row=e/5, seg=(e%5)*8;
    *reinterpret_cast<uint4*>(&Ks[row*LP+seg]) =
      *reinterpret_cast<const uint4*>(KV + ((size_t)b*kLC + row)*640 + hh*kDH + seg);
  }
  for (int e=tid; e<400; e+=256){               // Vt: 40 rows(d) x 10 seg(80 tok)
    int d=e/10, seg=(e%10)*8;
    *reinterpret_cast<uint4*>(&Vts[d*LP2+seg]) =
      *reinterpret_cast<const uint4*>(Vt2 + ((size_t)b*320 + hh*kDH + d)*80 + seg);
  }
  __syncthreads();
  const f32x4 zf = {0.f,0.f,0.f,0.f};
  f32x4 sacc[5] = {zf, zf, zf, zf, zf};
  bf16x8 aq0 = *reinterpret_cast<const bf16x8*>(&Qs[(wm+lr)*LP + quad*8]);
  bf16x8 aq1 = *reinterpret_cast<const bf16x8*>(&Qs[(wm+lr)*LP + 32 + quad*8]);
  #pragma unroll
  for (int j=0;j<5;j++){
    bf16x8 bk0 = *reinterpret_cast<const bf16x8*>(&Ks[(j*16+lr)*LP + quad*8]);
    sacc[j] = __builtin_amdgcn_mfma_f32_16x16x32_bf16(aq0, bk0, sacc[j], 0,0,0);
    bf16x8 bk1 = *reinterpret_cast<const bf16x8*>(&Ks[(j*16+lr)*LP + 32 + quad*8]);
    sacc[j] = __builtin_amdgcn_mfma_f32_16x16x32_bf16(aq1, bk1, sacc[j], 0,0,0);
  }
  float l_i[4];
  #pragma unroll
  for (int r=0;r<4;r++){
    float vv[5];
    float rm = -1e30f;
    #pragma unroll
    for (int j=0;j<5;j++){
      int c = j*16 + lr;
      vv[j] = sacc[j][r]*scale;
      if (c < kLC) rm = fmaxf(rm, vv[j]);
    }
    #pragma unroll
    for (int off=1; off<16; off<<=1) rm = fmaxf(rm, __shfl_xor(rm, off, 64));
    float psum = 0.f;
    int row = wm + quad*4 + r;
    #pragma unroll
    for (int j=0;j<5;j++){
      int c = j*16 + lr;
      float p = (c < kLC) ? __expf(vv[j]-rm) : 0.f;
      psum += p;
      Ps[row*LP2 + c] = f2b(p);
    }
    #pragma unroll
    for (int off=1; off<16; off<<=1) psum += __shfl_xor(psum, off, 64);
    l_i[r] = psum;
  }
  f32x4 oacc[3] = {zf, zf, zf};
  #pragma unroll
  for (int s=0;s<3;s++){
    bf16x8 ap = *reinterpret_cast<const bf16x8*>(&Ps[(wm+lr)*LP2 + s*32 + quad*8]);
    #pragma unroll
    for (int nt=0;nt<3;nt++){
      bf16x8 bv = *reinterpret_cast<const bf16x8*>(&Vts[(nt*16+lr)*LP2 + s*32 + quad*8]);
      oacc[nt] = __builtin_amdgcn_mfma_f32_16x16x32_bf16(ap, bv, oacc[nt], 0,0,0);
    }
  }
  #pragma unroll
  for (int r=0;r<4;r++){
    float inv = 1.0f / l_i[r];
    unsigned short* Ob = Oa + ((size_t)b*kN + q0 + wm + quad*4 + r)*kC + hh*kDH;
    #pragma unroll
    for (int nt=0;nt<3;nt++){
      int d = nt*16 + lr;
      if (d < kDH) Ob[d] = f2b(oacc[nt][r]*inv);
    }
  }
}

// ---------------- unmerge + residual ----------------
__global__ void k_unmerge(const float* __restrict__ net, const float* __restrict__ Xo,
                          const int* __restrict__ merged, const int* __restrict__ node_idx,
                          const int* __restrict__ slot_of, float* __restrict__ net1){
  int blk = blockIdx.x; int b = blk >> 12; int t = blk & 4095;
  int h = t>>6, w = t&63;
  int row;
  if (!((h|w)&1)) row = kNB + ((h>>1)*32 + (w>>1));
  else {
    int i = d_arank(h,w);
    row = merged[(size_t)b*kNA+i] ? (kNB + node_idx[(size_t)b*kNA+i]) : slot_of[(size_t)b*kNA+i];
  }
  const float* np_ = net + ((size_t)b*kN + t)*kC;
  const float* xp = Xo + ((size_t)b*kNM + row)*kC;
  float* op = net1 + ((size_t)b*kN + t)*kC;
  int lane = threadIdx.x;
  #pragma unroll
  for (int q=0;q<5;q++){ int c = lane+q*64; op[c] = np_[c] + xp[c]; }
}

// ---------------- launch ----------------
extern "C" void kernel_launch(void* const* d_in, const int* in_sizes, int n_in,
                              void* d_out, int out_size, void* d_ws, size_t ws_size,
                              hipStream_t stream){
  const float* net = (const float*)d_in[0];
  const float* ctx = (const float*)d_in[1];
  const float* ln1g=(const float*)d_in[2], *ln1b=(const float*)d_in[3];
  const float* ln2g=(const float*)d_in[4], *ln2b=(const float*)d_in[5];
  const float* ln3g=(const float*)d_in[6], *ln3b=(const float*)d_in[7];
  const float* w1q=(const float*)d_in[8],  *w1k=(const float*)d_in[9];
  const float* w1v=(const float*)d_in[10], *w1o=(const float*)d_in[11];
  const float* b1o=(const float*)d_in[12];
  const float* w2q=(const float*)d_in[13], *w2k=(const float*)d_in[14];
  const float* w2v=(const float*)d_in[15], *w2o=(const float*)d_in[16];
  const float* b2o=(const float*)d_in[17];
  const float* fw1=(const float*)d_in[18], *fb1=(const float*)d_in[19];
  const float* fw2=(const float*)d_in[20], *fb2=(const float*)d_in[21];

  char* ws = (char*)d_ws;
  float* mnA  = (float*)(ws + B_mnA);
  float* mnB  = (float*)(ws + B_mnB);
  float* y32  = (float*)(ws + B_y32);
  float* xm32 = (float*)(ws + B_xm);
  float* Xo1  = (float*)(ws + B_xo1);
  float* net1 = (float*)(ws + B_net1);
  float* net2 = (float*)(ws + B_net2);
  float* cnt  = (float*)(ws + B_cnt);
  unsigned short* Hb   = (unsigned short*)(ws + B_H);
  unsigned short* Gb   = (unsigned short*)(ws + B_G);
  unsigned short* QKb  = (unsigned short*)(ws + B_QKb);
  unsigned short* Vtg  = (unsigned short*)(ws + B_Vtg);
  unsigned short* yb   = (unsigned short*)(ws + B_yb);
  unsigned short* xmb  = (unsigned short*)(ws + B_xmb);
  unsigned short* Ao1b = (unsigned short*)(ws + B_Ao1b);
  unsigned short* Q2b  = (unsigned short*)(ws + B_Q2b);
  unsigned short* Ao2b = (unsigned short*)(ws + B_Ao2b);
  unsigned short* KV2b = (unsigned short*)(ws + B_KV2b);
  unsigned short* Vt2g = (unsigned short*)(ws + B_Vt2g);
  unsigned short* ctxb = (unsigned short*)(ws + B_ctxb);
  unsigned short* Wqkv = (unsigned short*)(ws + B_Wqkv);
  unsigned short* Wo1  = (unsigned short*)(ws + B_Wo1);
  unsigned short* Wq2  = (unsigned short*)(ws + B_Wq2);
  unsigned short* Wkv2 = (unsigned short*)(ws + B_Wkv2);
  unsigned short* Wo2  = (unsigned short*)(ws + B_Wo2);
  unsigned short* Wff1 = (unsigned short*)(ws + B_Wff1);
  unsigned short* Wff2 = (unsigned short*)(ws + B_Wff2);
  unsigned long long* pack = (unsigned long long*)(ws + B_pack);
  int* rnk  = (int*)(ws + B_rank);
  int* nidx = (int*)(ws + B_nidx); int* mrg = (int*)(ws + B_mrg); int* slot = (int*)(ws + B_slot);
  int* unml = (int*)(ws + B_unml); int* ucnt = (int*)(ws + B_ucnt); int* aidx = (int*)(ws + B_aidx);
  float* Opart = (float*)(ws + B_Op);
  float* lpart = (float*)(ws + B_lp);

  // --- batched weight conversion + ctx convert + Vt2 pad zero ---
  k_wt_all<<<628, 256, 0, stream>>>(w1q, w1k, w1v, w1o, w2q, w2k, w2v, w2o, fw1, fw2,
                                    Wqkv, Wo1, Wq2, Wkv2, Wo2, Wff1, Wff2, ctx, ctxb, Vt2g);

  // --- ToMe indices (exact fp32); gather absorbs idx/init/rank-zero ---
  k_gather<<<kB*kN, 64, 0, stream>>>(net, mnA, mnB, pack, ucnt, aidx, rnk);
  k_scores<<<dim3(kNA/128, kNB/64, kB), 256, 0, stream>>>(mnA, mnB, pack);
  k_rank_part  <<<dim3(kNA/256, kNA/256, kB), 256, 0, stream>>>(pack, rnk);
  k_rank_assign<<<dim3(kNA/256, kB), 256, 0, stream>>>(pack, rnk, nidx, mrg, slot, unml, ucnt);
  // --- merge(LN1(net)) ---
  k_ln<false><<<kB*kN, 64, 0, stream>>>(net, ln1g, ln1b, y32);
  k_merge_ud   <<<kB*kNB*2, 64, 0, stream>>>(y32, aidx, unml, xmb, xm32, cnt);
  k_merge_src  <<<kB*kNA, 64, 0, stream>>>(y32, aidx, mrg, nidx, xm32, cnt);
  k_merge_scale<<<kB*kNB, 64, 0, stream>>>(xm32, cnt, xmb);
  // --- attn1 (self, merged seq): QKV gemm writes Q|K rows + V transposed ---
  k_bgemm64<unsigned short,false,false,1><<<dim3(64,15), 256, 0, stream>>>(
      xmb, Wqkv, nullptr, nullptr, QKb, Vtg, 4096, 960, 320, 640);
  k_attn1<<<dim3((kNM/64)*2, kH, kB), 256, 0, stream>>>(QKb, Vtg, Opart, lpart);
  k_acomb<<<kB*kNM, 64, 0, stream>>>(Opart, lpart, Ao1b);
  k_bgemm64<float,true,false,0><<<dim3(64,5), 256, 0, stream>>>(
      Ao1b, Wo1, b1o, nullptr, Xo1, nullptr, 4096, 320, 320, 320);
  k_unmerge<<<kB*kN, 64, 0, stream>>>(net, Xo1, mrg, nidx, slot, net1);
  // --- attn2 (cross): KV2 gemm writes K rows + V2 transposed ---
  k_ln<true><<<kB*kN, 64, 0, stream>>>(net1, ln2g, ln2b, yb);
  k_bgemm64<unsigned short,false,false,0><<<dim3(128,5), 256, 0, stream>>>(
      yb, Wq2, nullptr, nullptr, Q2b, nullptr, 8192, 320, 320, 320);
  k_bgemm<unsigned short,false,false,2><<<dim3(2,5), 256, 0, stream>>>(
      ctxb, Wkv2, nullptr, nullptr, KV2b, Vt2g, 154, 640, 768, 640);
  k_attn2m<<<dim3(kN/64, kH, kB), 256, 0, stream>>>(Q2b, KV2b, Vt2g, Ao2b);
  k_bgemm64<float,true,true,0><<<dim3(128,5), 256, 0, stream>>>(
      Ao2b, Wo2, b2o, net1, net2, nullptr, 8192, 320, 320, 320);
  // --- GEGLU FF ---
  k_ln<true><<<kB*kN, 64, 0, stream>>>(net2, ln3g, ln3b, yb);
  k_bgemm<unsigned short,true,false,0><<<dim3(64,20), 256, 0, stream>>>(
      yb, Wff1, fb1, nullptr, Hb, nullptr, 8192, 2560, 320, 2560);
  k_geglu<<<(kB*kN*160+255)/256, 256, 0, stream>>>(Hb, Gb);
  k_bgemm64<float,true,true,0><<<dim3(128,5), 256, 0, stream>>>(
      Gb, Wff2, fb2, net2, (float*)d_out, nullptr, 8192, 320, 1280, 320);
}

// Round 12
// 470.601 us; speedup vs baseline: 1.0430x; 1.0430x over previous
//
#include <hip/hip_runtime.h>

typedef __attribute__((ext_vector_type(8))) short bf16x8;
typedef __attribute__((ext_vector_type(4))) float f32x4;

// ---------------- problem constants ----------------
constexpr int kB   = 2;
constexpr int kN   = 4096;   // tokens (64x64)
constexpr int kC   = 320;    // channels
constexpr int kNA  = 3072;   // src (non-dst) tokens
constexpr int kNB  = 1024;   // dst tokens
constexpr int kNM  = 2048;   // merged seq len
constexpr int kR   = 2048;   // merged src count
constexpr int kH   = 8;
constexpr int kDH  = 40;
constexpr int kLC  = 77;
constexpr int kDC  = 768;
constexpr int kDFF = 1280;

__device__ __forceinline__ unsigned short f2b(float f){
  unsigned u = __float_as_uint(f);
  u += 0x7FFF + ((u>>16)&1);
  return (unsigned short)(u>>16);
}
__device__ __forceinline__ float b2f(unsigned short h){ return __uint_as_float(((unsigned)h)<<16); }

__device__ __forceinline__ float wave_sum(float v){
  #pragma unroll
  for (int m=32;m>=1;m>>=1) v += __shfl_xor(v, m, 64);
  return v;
}
__device__ __forceinline__ int d_arank(int h, int w){
  int base = 32*((h+1)>>1) + 64*(h>>1);
  return base + ((h&1) ? w : (w>>1));
}

// ---------------- ws layout (byte offsets) ----------------
constexpr size_t rndB(size_t x){ return (x + 255) & ~(size_t)255; }
constexpr size_t B_mnA  = 0;                                             // fp32 [2*3072*320]
constexpr size_t B_mnB  = rndB(B_mnA + (size_t)kB*kNA*kC*4);             // fp32 [2*1024*320]
constexpr size_t B_y32  = rndB(B_mnB + (size_t)kB*kNB*kC*4);             // fp32 [2*4096*320] (LN1)
constexpr size_t B_xm   = rndB(B_y32 + (size_t)kB*kN*kC*4);              // fp32 [2*2048*320]
constexpr size_t B_xo1  = rndB(B_xm  + (size_t)kB*kNM*kC*4);             // fp32 [2*2048*320]
constexpr size_t B_net1 = rndB(B_xo1 + (size_t)kB*kNM*kC*4);             // fp32 [2*4096*320]
constexpr size_t B_H    = 0;  // bf16 [8192*2560] overlays mnA..net1 (41.94 MB, all dead by then)
constexpr size_t B_net2 = rndB(B_net1 + (size_t)kB*kN*kC*4);             // fp32 [2*4096*320]
constexpr size_t B_G    = rndB(B_net2 + (size_t)kB*kN*kC*4);             // bf16 [8192*1280]
constexpr size_t B_QKb  = rndB(B_G    + (size_t)kB*kN*kDFF*2);           // bf16 [4096*640] (Q|K)
constexpr size_t B_Vtg  = rndB(B_QKb  + (size_t)kB*kNM*640*2);           // bf16 [320*4096] (V^T)
constexpr size_t B_yb   = rndB(B_Vtg  + (size_t)320*kB*kNM*2);           // bf16 [8192*320]
constexpr size_t B_xmb  = rndB(B_yb   + (size_t)kB*kN*kC*2);             // bf16 [4096*320]
constexpr size_t B_Ao1b = rndB(B_xmb  + (size_t)kB*kNM*kC*2);            // bf16 [4096*320]
constexpr size_t B_Q2b  = rndB(B_Ao1b + (size_t)kB*kNM*kC*2);            // bf16 [8192*320]
constexpr size_t B_Ao2b = rndB(B_Q2b  + (size_t)kB*kN*kC*2);             // bf16 [8192*320]
constexpr size_t B_KV2b = rndB(B_Ao2b + (size_t)kB*kN*kC*2);             // bf16 [154*640]
constexpr size_t B_Vt2g = rndB(B_KV2b + (size_t)kB*kLC*640*2);           // bf16 [2*320*80] (V2^T pad)
constexpr size_t B_ctxb = rndB(B_Vt2g + (size_t)kB*320*80*2);            // bf16 [154*768]
constexpr size_t B_Wqkv = rndB(B_ctxb + (size_t)kB*kLC*kDC*2);           // bf16 [960*320]
constexpr size_t B_Wo1  = rndB(B_Wqkv + (size_t)960*320*2);              // bf16 [320*320]
constexpr size_t B_Wq2  = rndB(B_Wo1  + (size_t)320*320*2);
constexpr size_t B_Wkv2 = rndB(B_Wq2  + (size_t)320*320*2);              // bf16 [640*768]
constexpr size_t B_Wo2  = rndB(B_Wkv2 + (size_t)640*768*2);
constexpr size_t B_Wff1 = rndB(B_Wo2  + (size_t)320*320*2);              // bf16 [2560*320]
constexpr size_t B_Wff2 = rndB(B_Wff1 + (size_t)2560*320*2);             // bf16 [320*1280]
constexpr size_t B_cnt  = rndB(B_Wff2 + (size_t)320*1280*2);             // fp32 [2*1024]
constexpr size_t B_pack = rndB(B_cnt  + (size_t)kB*kNB*4);               // u64 [2*3072]
constexpr size_t B_rank = rndB(B_pack + (size_t)kB*kNA*8);               // int [2*3072]
constexpr size_t B_nidx = rndB(B_rank + (size_t)kB*kNA*4);
constexpr size_t B_mrg  = rndB(B_nidx + (size_t)kB*kNA*4);
constexpr size_t B_slot = rndB(B_mrg  + (size_t)kB*kNA*4);
constexpr size_t B_unml = rndB(B_slot + (size_t)kB*kNA*4);
constexpr size_t B_ucnt = rndB(B_unml + (size_t)kB*kNB*4);
constexpr size_t B_aidx = rndB(B_ucnt + 64);

// ---------------- gather + (idx/init/rank-zero absorbed) ----------------
__global__ void k_gather(const float* __restrict__ net, float* __restrict__ mA, float* __restrict__ mB,
                         unsigned long long* __restrict__ pack, int* __restrict__ ucnt,
                         int* __restrict__ a_idx, int* __restrict__ rank){
  int blk = blockIdx.x; int b = blk >> 12; int t = blk & 4095;
  int lane = threadIdx.x;
  int gid = blk*64 + lane;
  if (gid < kB*kNA){ pack[gid] = 0ull; rank[gid] = 0; }
  if (gid < kB) ucnt[gid] = 0;
  if (gid < kN){
    int h = gid>>6, w = gid&63;
    if ((h|w)&1) a_idx[d_arank(h,w)] = gid;
  }
  const float* xp = net + ((size_t)b*kN + t)*kC;
  float v[5]; float s2 = 0.f;
  #pragma unroll
  for (int i=0;i<5;i++){ float f = xp[lane + i*64]; v[i]=f; s2 += f*f; }
  s2 = wave_sum(s2);
  float rn = 1.0f / sqrtf(s2);
  int h=t>>6, w=t&63;
  float* dp;
  if (!((h|w)&1)) dp = mB + ((size_t)b*kNB + ((h>>1)*32+(w>>1)))*kC;
  else            dp = mA + ((size_t)b*kNA + d_arank(h,w))*kC;
  #pragma unroll
  for (int i=0;i<5;i++) dp[lane + i*64] = v[i]*rn;
}

// ---------------- fused score GEMM (NT, exact fp32, 128x64 tile, 8x4 microtile) + row argmax ----------------
__global__ __launch_bounds__(256) void k_scores(const float* __restrict__ mA, const float* __restrict__ mB,
                                                unsigned long long* __restrict__ pack){
  __shared__ __align__(16) float As[16][136];   // [k][m 0..127]
  __shared__ __align__(16) float Bs[16][68];    // [k][n 0..63]
  const int b = blockIdx.z;
  const int m0 = blockIdx.x*128, n0 = blockIdx.y*64;
  const int tid = threadIdx.x;
  const int mr = tid>>4, nc = tid&15;           // rows m0+mr*8.., cols n0+nc*4..
  const float* Ab = mA + (size_t)b*kNA*kC;
  const float* Bb = mB + (size_t)b*kNB*kC;
  float acc[8][4] = {};
  const int ar = tid>>1, ac8 = (tid&1)*8;       // A staging: row, col-octet
  const int br = tid>>2, bc4 = (tid&3)*4;       // B staging
  for (int k0=0; k0<kC; k0+=16){
    __syncthreads();
    {
      float4 a0 = *reinterpret_cast<const float4*>(&Ab[(size_t)(m0+ar)*kC + k0 + ac8]);
      float4 a1 = *reinterpret_cast<const float4*>(&Ab[(size_t)(m0+ar)*kC + k0 + ac8 + 4]);
      As[ac8+0][ar]=a0.x; As[ac8+1][ar]=a0.y; As[ac8+2][ar]=a0.z; As[ac8+3][ar]=a0.w;
      As[ac8+4][ar]=a1.x; As[ac8+5][ar]=a1.y; As[ac8+6][ar]=a1.z; As[ac8+7][ar]=a1.w;
      float4 bv = *reinterpret_cast<const float4*>(&Bb[(size_t)(n0+br)*kC + k0 + bc4]);
      Bs[bc4+0][br]=bv.x; Bs[bc4+1][br]=bv.y; Bs[bc4+2][br]=bv.z; Bs[bc4+3][br]=bv.w;
    }
    __syncthreads();
    #pragma unroll
    for (int kk=0;kk<16;kk++){
      const float4 a4a = *reinterpret_cast<const float4*>(&As[kk][mr*8]);
      const float4 a4b = *reinterpret_cast<const float4*>(&As[kk][mr*8+4]);
      const float4 b4  = *reinterpret_cast<const float4*>(&Bs[kk][nc*4]);
      const float aa[8]={a4a.x,a4a.y,a4a.z,a4a.w,a4b.x,a4b.y,a4b.z,a4b.w};
      const float bb[4]={b4.x,b4.y,b4.z,b4.w};
      #pragma unroll
      for (int i=0;i<8;i++)
        #pragma unroll
        for (int j=0;j<4;j++)
          acc[i][j] = fmaf(aa[i], bb[j], acc[i][j]);
    }
  }
  #pragma unroll
  for (int i=0;i<8;i++){
    float bs = acc[i][0]; int bj = n0 + nc*4;
    #pragma unroll
    for (int j=1;j<4;j++){
      float v = acc[i][j];
      if (v > bs){ bs=v; bj=n0+nc*4+j; }
    }
    #pragma unroll
    for (int off=1; off<16; off<<=1){
      float os = __shfl_xor(bs, off, 16);
      int   oj = __shfl_xor(bj, off, 16);
      if (os > bs || (os == bs && oj < bj)){ bs=os; bj=oj; }
    }
    if (nc == 0){
      unsigned int u = __float_as_uint(bs);
      unsigned int key = (u & 0x80000000u) ? ~u : (u | 0x80000000u);
      unsigned long long pk = ((unsigned long long)key << 32) |
                              (unsigned long long)(0xFFFFFFFFu - (unsigned int)bj);
      atomicMax(&pack[(size_t)b*kNA + m0 + mr*8 + i], pk);
    }
  }
}
// partial rank over a 256-key j-chunk (grid: 12 i-blocks x 12 j-chunks x 2 batches)
__global__ __launch_bounds__(256) void k_rank_part(const unsigned long long* __restrict__ pack,
                                                   int* __restrict__ rank){
  __shared__ unsigned int keys[256];
  const int b = blockIdx.z;
  const int i = blockIdx.x*256 + threadIdx.x;
  const int j0 = blockIdx.y*256;
  const unsigned long long* pb = pack + (size_t)b*kNA;
  keys[threadIdx.x] = (unsigned int)(pb[j0 + threadIdx.x]>>32);
  unsigned int ki = (unsigned int)(pb[i]>>32);
  __syncthreads();
  int cnt = 0;
  #pragma unroll 8
  for (int jj=0;jj<256;jj++){
    unsigned int kj = keys[jj];
    int j = j0 + jj;
    cnt += (kj > ki) || (kj == ki && j < i);
  }
  atomicAdd(&rank[(size_t)b*kNA + i], cnt);
}
// decode node_idx + merged/slot assignment from accumulated rank
__global__ void k_rank_assign(const unsigned long long* __restrict__ pack, const int* __restrict__ rank,
                              int* __restrict__ node_idx, int* __restrict__ merged,
                              int* __restrict__ slot_of, int* __restrict__ unm_list,
                              int* __restrict__ ucnt){
  int b = blockIdx.y;
  int i = blockIdx.x*256 + threadIdx.x;
  unsigned long long p = pack[(size_t)b*kNA + i];
  node_idx[(size_t)b*kNA + i] = (int)(0xFFFFFFFFu - (unsigned int)(p & 0xFFFFFFFFull));
  int mg = rank[(size_t)b*kNA + i] < kR;
  merged[(size_t)b*kNA + i] = mg;
  if (!mg){
    int s = atomicAdd(&ucnt[b], 1);
    unm_list[(size_t)b*kNB + s] = i;
    slot_of[(size_t)b*kNA + i] = s;
  }
}

// ---------------- layernorm (OB: bf16 out) ----------------
template<bool OB>
__global__ void k_ln(const float* __restrict__ x, const float* __restrict__ g,
                     const float* __restrict__ be, void* __restrict__ yv){
  const int row = blockIdx.x;
  const int lane = threadIdx.x;
  const float* xp = x + (size_t)row*kC;
  float v[5]; float s=0.f, s2=0.f;
  #pragma unroll
  for (int i=0;i<5;i++){ float f = xp[lane + i*64]; v[i]=f; s+=f; s2+=f*f; }
  s = wave_sum(s); s2 = wave_sum(s2);
  float mu = s * (1.0f/kC);
  float var = s2 * (1.0f/kC) - mu*mu;
  float rstd = rsqrtf(var + 1e-5f);
  #pragma unroll
  for (int i=0;i<5;i++){
    int c = lane + i*64;
    float o = (v[i]-mu)*rstd*g[c] + be[c];
    if (OB) ((unsigned short*)yv)[(size_t)row*kC + c] = f2b(o);
    else    ((float*)yv)[(size_t)row*kC + c] = o;
  }
}

// ---------------- merge (unm + dst fused; src; scale) ----------------
__global__ void k_merge_ud(const float* __restrict__ y, const int* __restrict__ a_idx,
                           const int* __restrict__ unm_list, unsigned short* __restrict__ xmb,
                           float* __restrict__ xm, float* __restrict__ cnt){
  int blk = blockIdx.x;
  int lane = threadIdx.x;
  if (blk < kB*kNB){
    int b = blk >> 10; int s = blk & 1023;
    int i = unm_list[(size_t)b*kNB + s];
    int t = a_idx[i];
    const float* sp = y + ((size_t)b*kN + t)*kC;
    unsigned short* dp = xmb + ((size_t)b*kNM + s)*kC;
    #pragma unroll
    for (int q=0;q<5;q++) dp[lane+q*64] = f2b(sp[lane+q*64]);
  } else {
    blk -= kB*kNB;
    int b = blk >> 10; int j = blk & 1023;
    int t = 128*(j>>5) + 2*(j&31);
    const float* sp = y + ((size_t)b*kN + t)*kC;
    float* dp = xm + ((size_t)b*kNM + kNB + j)*kC;
    #pragma unroll
    for (int q=0;q<5;q++) dp[lane+q*64] = sp[lane+q*64];
    if (lane==0) cnt[(size_t)b*kNB + j] = 1.0f;
  }
}
__global__ void k_merge_src(const float* __restrict__ y, const int* __restrict__ a_idx,
                            const int* __restrict__ merged, const int* __restrict__ node_idx,
                            float* __restrict__ xm, float* __restrict__ cnt){
  int blk = blockIdx.x; int b = blk / kNA; int i = blk % kNA;
  if (!merged[(size_t)b*kNA + i]) return;
  int t = a_idx[i]; int j = node_idx[(size_t)b*kNA + i];
  const float* sp = y + ((size_t)b*kN + t)*kC;
  float* dp = xm + ((size_t)b*kNM + kNB + j)*kC;
  int lane = threadIdx.x;
  #pragma unroll
  for (int q=0;q<5;q++) atomicAdd(&dp[lane+q*64], sp[lane+q*64]);
  if (lane==0) atomicAdd(&cnt[(size_t)b*kNB + j], 1.0f);
}
__global__ void k_merge_scale(const float* __restrict__ xm, const float* __restrict__ cnt,
                              unsigned short* __restrict__ xmb){
  int blk = blockIdx.x; int b = blk >> 10; int j = blk & 1023;
  float inv = 1.0f / cnt[(size_t)b*kNB + j];
  const float* sp = xm + ((size_t)b*kNM + kNB + j)*kC;
  unsigned short* dp = xmb + ((size_t)b*kNM + kNB + j)*kC;
  int lane = threadIdx.x;
  #pragma unroll
  for (int q=0;q<5;q++) dp[lane+q*64] = f2b(sp[lane+q*64]*inv);
}

// ---------------- batched weight transpose+convert + ctx convert + Vt2 pad zero ----------------
__global__ __launch_bounds__(256) void k_wt_all(
    const float* __restrict__ w0, const float* __restrict__ w1, const float* __restrict__ w2,
    const float* __restrict__ w3, const float* __restrict__ w4, const float* __restrict__ w5,
    const float* __restrict__ w6, const float* __restrict__ w7, const float* __restrict__ w8,
    const float* __restrict__ w9,
    unsigned short* __restrict__ Wqkv, unsigned short* __restrict__ Wo1,
    unsigned short* __restrict__ Wq2,  unsigned short* __restrict__ Wkv2,
    unsigned short* __restrict__ Wo2,  unsigned short* __restrict__ Wff1,
    unsigned short* __restrict__ Wff2,
    const float* __restrict__ ctx, unsigned short* __restrict__ ctxb,
    unsigned short* __restrict__ Vt2){
  const int bid = blockIdx.x;
  const int tid = threadIdx.x;
  if (bid >= 570){
    int base = (bid-570)*2048 + tid*8;
    #pragma unroll
    for (int j=0;j<8;j++){
      int i = base + j;
      if (i < kB*kLC*kDC) ctxb[i] = f2b(ctx[i]);
    }
    if (bid == 570){
      for (int r=tid; r<kB*320; r+=256){
        Vt2[(size_t)r*80 + 77] = 0; Vt2[(size_t)r*80 + 78] = 0; Vt2[(size_t)r*80 + 79] = 0;
      }
    }
    return;
  }
  const int jb[11]   = {0,25,50,75,100,125,185,245,270,470,570};
  const float* srcs[10] = {w0,w1,w2,w3,w4,w5,w6,w7,w8,w9};
  unsigned short* dsts[10] = {Wqkv, Wqkv+320*320, Wqkv+640*320, Wo1, Wq2,
                              Wkv2, Wkv2+320*768, Wo2, Wff1, Wff2};
  const int Kd[10] = {320,320,320,320,320,768,768,320,320,1280};
  const int Nd[10] = {320,320,320,320,320,320,320,320,2560,320};
  int job = 0;
  while (bid >= jb[job+1]) job++;
  int local = bid - jb[job];
  const int Nt = (Nd[job]+63)>>6;
  int k0 = (local / Nt)*64, n0 = (local % Nt)*64;
  const float* W = srcs[job];
  unsigned short* Wt = dsts[job];
  const int K = Kd[job], N = Nd[job];
  __shared__ float tile[64][65];
  #pragma unroll
  for (int l=0;l<16;l++){
    int e = tid + l*256; int r = e>>6, c = e&63;
    int gk = k0+r, gn = n0+c;
    tile[r][c] = (gk<K && gn<N) ? W[(size_t)gk*N+gn] : 0.f;
  }
  __syncthreads();
  #pragma unroll
  for (int l=0;l<16;l++){
    int e = tid + l*256; int r = e>>6, c = e&63;
    int gn = n0+r, gk = k0+c;
    if (gn<N && gk<K) Wt[(size_t)gn*K+gk] = f2b(tile[c][r]);
  }
}

// ---------------- bf16 MFMA GEMM 128x128: out = A @ Bt^T (+bias)(+resid) ----------------
template<typename OT, bool BIAS, bool RES, int SVM>
__global__ __launch_bounds__(256) void k_bgemm(const unsigned short* __restrict__ A,
    const unsigned short* __restrict__ Bt, const float* __restrict__ bias,
    const float* __restrict__ resid, OT* __restrict__ out, unsigned short* __restrict__ vt,
    int M, int N, int K, int ldo){
  constexpr int LDK = 72;
  __shared__ unsigned short As[128*LDK];
  __shared__ unsigned short Bs[128*LDK];
  const int tid = threadIdx.x;
  const int m0 = blockIdx.x*128, n0 = blockIdx.y*128;
  const int wid = tid>>6, lane = tid&63;
  const int wm = (wid>>1)*64, wn = (wid&1)*64;
  const int lr = lane&15, quad = lane>>4;
  const f32x4 zero4 = {0.f,0.f,0.f,0.f};
  f32x4 acc[4][4];
  #pragma unroll
  for (int i=0;i<4;i++)
    #pragma unroll
    for (int j=0;j<4;j++) acc[i][j] = zero4;
  for (int k0=0; k0<K; k0+=64){
    __syncthreads();
    #pragma unroll
    for (int l=0;l<4;l++){
      int e = tid + l*256;
      int row = e>>3, seg = (e&7)*8;
      int gm = m0+row;
      uint4 va = (gm<M) ? *reinterpret_cast<const uint4*>(&A[(size_t)gm*K + k0 + seg])
                        : make_uint4(0u,0u,0u,0u);
      *reinterpret_cast<uint4*>(&As[row*LDK + seg]) = va;
      int gn = n0+row;
      uint4 vb = (gn<N) ? *reinterpret_cast<const uint4*>(&Bt[(size_t)gn*K + k0 + seg])
                        : make_uint4(0u,0u,0u,0u);
      *reinterpret_cast<uint4*>(&Bs[row*LDK + seg]) = vb;
    }
    __syncthreads();
    #pragma unroll
    for (int kk=0; kk<64; kk+=32){
      bf16x8 af[4], bfr[4];
      #pragma unroll
      for (int i=0;i<4;i++) af[i]  = *reinterpret_cast<const bf16x8*>(&As[(wm+i*16+lr)*LDK + kk + quad*8]);
      #pragma unroll
      for (int j=0;j<4;j++) bfr[j] = *reinterpret_cast<const bf16x8*>(&Bs[(wn+j*16+lr)*LDK + kk + quad*8]);
      #pragma unroll
      for (int i=0;i<4;i++)
        #pragma unroll
        for (int j=0;j<4;j++)
          acc[i][j] = __builtin_amdgcn_mfma_f32_16x16x32_bf16(af[i], bfr[j], acc[i][j], 0, 0, 0);
    }
  }
  #pragma unroll
  for (int i=0;i<4;i++){
    #pragma unroll
    for (int j=0;j<4;j++){
      int gn = n0 + wn + j*16 + lr;
      if (gn >= N) continue;
      float bv = BIAS ? bias[gn] : 0.f;
      #pragma unroll
      for (int r=0;r<4;r++){
        int gm = m0 + wm + i*16 + quad*4 + r;
        if (gm >= M) continue;
        float v = acc[i][j][r] + bv;
        if (RES) v += resid[(size_t)gm*ldo + gn];
        if (SVM == 1 && gn >= 640){
          vt[(size_t)(gn-640)*4096 + gm] = f2b(v);
        } else if (SVM == 2 && gn >= 320){
          int bb = gm / 77, tok = gm - bb*77;
          vt[((size_t)bb*320 + (gn-320))*80 + tok] = f2b(v);
        } else {
          if constexpr (sizeof(OT)==2) out[(size_t)gm*ldo + gn] = (OT)f2b(v);
          else                         out[(size_t)gm*ldo + gn] = (OT)v;
        }
      }
    }
  }
}

// ---------------- bf16 MFMA GEMM 64x64 tile (high-occupancy, for narrow-N GEMMs) ----------------
template<typename OT, bool BIAS, bool RES, int SVM>
__global__ __launch_bounds__(256) void k_bgemm64(const unsigned short* __restrict__ A,
    const unsigned short* __restrict__ Bt, const float* __restrict__ bias,
    const float* __restrict__ resid, OT* __restrict__ out, unsigned short* __restrict__ vt,
    int M, int N, int K, int ldo){
  constexpr int LDK = 72;
  __shared__ unsigned short As[64*LDK];
  __shared__ unsigned short Bs[64*LDK];
  const int tid = threadIdx.x;
  const int m0 = blockIdx.x*64, n0 = blockIdx.y*64;
  const int wid = tid>>6, lane = tid&63;
  const int wm = (wid>>1)*32, wn = (wid&1)*32;
  const int lr = lane&15, quad = lane>>4;
  const f32x4 zero4 = {0.f,0.f,0.f,0.f};
  f32x4 acc[2][2];
  #pragma unroll
  for (int i=0;i<2;i++)
    #pragma unroll
    for (int j=0;j<2;j++) acc[i][j] = zero4;
  for (int k0=0; k0<K; k0+=64){
    __syncthreads();
    #pragma unroll
    for (int l=0;l<2;l++){
      int e = tid + l*256;
      int row = e>>3, seg = (e&7)*8;
      int gm = m0+row;
      uint4 va = (gm<M) ? *reinterpret_cast<const uint4*>(&A[(size_t)gm*K + k0 + seg])
                        : make_uint4(0u,0u,0u,0u);
      *reinterpret_cast<uint4*>(&As[row*LDK + seg]) = va;
      int gn = n0+row;
      uint4 vb = (gn<N) ? *reinterpret_cast<const uint4*>(&Bt[(size_t)gn*K + k0 + seg])
                        : make_uint4(0u,0u,0u,0u);
      *reinterpret_cast<uint4*>(&Bs[row*LDK + seg]) = vb;
    }
    __syncthreads();
    #pragma unroll
    for (int kk=0; kk<64; kk+=32){
      bf16x8 af[2], bfr[2];
      #pragma unroll
      for (int i=0;i<2;i++) af[i]  = *reinterpret_cast<const bf16x8*>(&As[(wm+i*16+lr)*LDK + kk + quad*8]);
      #pragma unroll
      for (int j=0;j<2;j++) bfr[j] = *reinterpret_cast<const bf16x8*>(&Bs[(wn+j*16+lr)*LDK + kk + quad*8]);
      #pragma unroll
      for (int i=0;i<2;i++)
        #pragma unroll
        for (int j=0;j<2;j++)
          acc[i][j] = __builtin_amdgcn_mfma_f32_16x16x32_bf16(af[i], bfr[j], acc[i][j], 0, 0, 0);
    }
  }
  #pragma unroll
  for (int i=0;i<2;i++){
    #pragma unroll
    for (int j=0;j<2;j++){
      int gn = n0 + wn + j*16 + lr;
      if (gn >= N) continue;
      float bv = BIAS ? bias[gn] : 0.f;
      #pragma unroll
      for (int r=0;r<4;r++){
        int gm = m0 + wm + i*16 + quad*4 + r;
        if (gm >= M) continue;
        float v = acc[i][j][r] + bv;
        if (RES) v += resid[(size_t)gm*ldo + gn];
        if (SVM == 1 && gn >= 640){
          vt[(size_t)(gn-640)*4096 + gm] = f2b(v);
        } else if (SVM == 2 && gn >= 320){
          int bb = gm / 77, tok = gm - bb*77;
          vt[((size_t)bb*320 + (gn-320))*80 + tok] = f2b(v);
        } else {
          if constexpr (sizeof(OT)==2) out[(size_t)gm*ldo + gn] = (OT)f2b(v);
          else                         out[(size_t)gm*ldo + gn] = (OT)v;
        }
      }
    }
  }
}

// ---------------- GEGLU elementwise: G = H[:, :1280] * gelu(H[:, 1280:]) ----------------
__global__ void k_geglu(const unsigned short* __restrict__ H, unsigned short* __restrict__ G){
  int e = blockIdx.x*256 + threadIdx.x;   // 8192*160 threads
  int m = e/160, t = e - m*160;
  const unsigned short* hp = H + (size_t)m*2560 + t*8;
  uint4 xv = *reinterpret_cast<const uint4*>(hp);
  uint4 gv = *reinterpret_cast<const uint4*>(hp + 1280);
  const unsigned short* xu = reinterpret_cast<const unsigned short*>(&xv);
  const unsigned short* gu = reinterpret_cast<const unsigned short*>(&gv);
  unsigned short ov[8];
  #pragma unroll
  for (int d=0; d<8; d++){
    float x = b2f(xu[d]);
    float g = b2f(gu[d]);
    float ge = 0.5f*g*(1.0f + erff(g*0.70710678118654752f));
    ov[d] = f2b(x*ge);
  }
  *reinterpret_cast<uint4*>(G + (size_t)m*1280 + t*8) = *reinterpret_cast<const uint4*>(ov);
}

// ---------------- MFMA flash self-attn (single-pass, reg-Q, shift-free softmax) ----------------
__global__ __launch_bounds__(256) void k_attn1(const unsigned short* __restrict__ QK,
                                               const unsigned short* __restrict__ Vtg,
                                               unsigned short* __restrict__ Oa){
  constexpr int LP = 72, LV = 136;
  __shared__ unsigned short Ks[128*LP];   // [key][d pad64]
  __shared__ unsigned short Vt[48*LV];    // [d pad48][key 128 pad136]
  __shared__ unsigned short Ps[64*LV];    // [q][key 128 pad136]
  const int b = blockIdx.z, hh = blockIdx.y;
  const int q0 = blockIdx.x*64;
  const int tid = threadIdx.x;
  const int wid = tid>>6, lane = tid&63;
  const int lr = lane&15, quad = lane>>4;
  const int wm = wid*16;
  const float scale = 0.15811388300841898f; // 1/sqrt(40)
  const unsigned short* Kb = QK + ((size_t)b*kNM)*640 + 320 + hh*kDH;
  const unsigned short* Vb = Vtg + (size_t)hh*kDH*4096 + (size_t)b*kNM;
  const uint4 z4 = make_uint4(0u,0u,0u,0u);
  // Q fragments: direct per-lane 16B global loads (A-layout). Cols 40.. are pad -> zero.
  const unsigned short* Qrow = QK + ((size_t)b*kNM + q0 + wm + lr)*640 + hh*kDH;
  bf16x8 aq0 = *reinterpret_cast<const bf16x8*>(Qrow + quad*8);
  bf16x8 aq1 = {0,0,0,0,0,0,0,0};
  if (quad == 0) aq1 = *reinterpret_cast<const bf16x8*>(Qrow + 32);
  // zero pads: Ks cols 40..63 (128 x 3 segs), Vt rows 40..47 (8 x 17 segs)
  for (int e=tid; e<384; e+=256){
    int row=e/3, seg=40+(e%3)*8;
    *reinterpret_cast<uint4*>(&Ks[row*LP+seg]) = z4;
  }
  for (int e=tid; e<136; e+=256){
    int row=40+e/17, seg=(e%17)*8;
    *reinterpret_cast<uint4*>(&Vt[row*LV+seg]) = z4;
  }
  const f32x4 zf = {0.f,0.f,0.f,0.f};
  f32x4 oacc[3] = {zf, zf, zf};
  float l_i[4] = {0.f, 0.f, 0.f, 0.f};
  for (int kt=0; kt<kNM; kt+=128){
    __syncthreads();
    for (int e=tid; e<640; e+=256){          // K: 128 rows x 5 segs
      int row=e/5, seg=(e%5)*8;
      *reinterpret_cast<uint4*>(&Ks[row*LP+seg]) =
        *reinterpret_cast<const uint4*>(Kb + (size_t)(kt+row)*640 + seg);
    }
    for (int e=tid; e<640; e+=256){          // Vt: 40 d-rows x 16 segs (128 tokens)
      int d=e>>4, seg=(e&15)*8;
      *reinterpret_cast<uint4*>(&Vt[d*LV+seg]) =
        *reinterpret_cast<const uint4*>(Vb + (size_t)d*4096 + kt + seg);
    }
    __syncthreads();
    f32x4 sacc[8];
    #pragma unroll
    for (int j=0;j<8;j++){
      bf16x8 bk0 = *reinterpret_cast<const bf16x8*>(&Ks[(j*16+lr)*LP + quad*8]);
      sacc[j] = __builtin_amdgcn_mfma_f32_16x16x32_bf16(aq0, bk0, zf, 0,0,0);
      bf16x8 bk1 = *reinterpret_cast<const bf16x8*>(&Ks[(j*16+lr)*LP + 32 + quad*8]);
      sacc[j] = __builtin_amdgcn_mfma_f32_16x16x32_bf16(aq1, bk1, sacc[j], 0,0,0);
    }
    #pragma unroll
    for (int r=0;r<4;r++){
      int row = wm + quad*4 + r;
      float psum = 0.f;
      #pragma unroll
      for (int j=0;j<8;j++){
        float p = __expf(sacc[j][r]*scale);
        psum += p;
        Ps[row*LV + j*16 + lr] = f2b(p);
      }
      #pragma unroll
      for (int off=1; off<16; off<<=1) psum += __shfl_xor(psum, off, 64);
      l_i[r] += psum;
    }
    #pragma unroll
    for (int s=0;s<4;s++){
      bf16x8 ap = *reinterpret_cast<const bf16x8*>(&Ps[(wm+lr)*LV + s*32 + quad*8]);
      #pragma unroll
      for (int nt=0;nt<3;nt++){
        bf16x8 bv = *reinterpret_cast<const bf16x8*>(&Vt[(nt*16+lr)*LV + s*32 + quad*8]);
        oacc[nt] = __builtin_amdgcn_mfma_f32_16x16x32_bf16(ap, bv, oacc[nt], 0,0,0);
      }
    }
  }
  // epilogue: O[m][d], m = wm+quad*4+r, d = nt*16+lr (d<40)
  #pragma unroll
  for (int r=0;r<4;r++){
    float inv = 1.0f / l_i[r];
    unsigned short* Ob = Oa + ((size_t)b*kNM + q0 + wm + quad*4 + r)*kC + hh*kDH;
    #pragma unroll
    for (int nt=0;nt<3;nt++){
      int d = nt*16 + lr;
      if (d < kDH) Ob[d] = f2b(oacc[nt][r]*inv);
    }
  }
}

// ---------------- MFMA one-shot cross-attn: 64 q/block, 77 keys pad 80 ----------------
__global__ __launch_bounds__(256) void k_attn2m(const unsigned short* __restrict__ Q,
                                                const unsigned short* __restrict__ KV,
                                                const unsigned short* __restrict__ Vt2,
                                                unsigned short* __restrict__ Oa){
  constexpr int LP = 72, LP2 = 104;
  __shared__ unsigned short Qs[64*LP];    // [q][d pad64]
  __shared__ unsigned short Ks[80*LP];    // [key pad80][d pad64]
  __shared__ unsigned short Vts[48*LP2];  // [d pad48][key pad96]
  __shared__ unsigned short Ps[64*LP2];   // [q][key pad96]
  const int b = blockIdx.z, hh = blockIdx.y;
  const int q0 = blockIdx.x*64;
  const int tid = threadIdx.x;
  const int wid = tid>>6, lane = tid&63;
  const int lr = lane&15, quad = lane>>4;
  const int wm = wid*16;
  const float scale = 0.15811388300841898f;
  const uint4 z4 = make_uint4(0u,0u,0u,0u);
  for (int e=tid; e<576; e+=256) *reinterpret_cast<uint4*>(&Qs[e*8]) = z4;   // 64*72/8
  for (int e=tid; e<720; e+=256) *reinterpret_cast<uint4*>(&Ks[e*8]) = z4;   // 80*72/8
  for (int e=tid; e<624; e+=256) *reinterpret_cast<uint4*>(&Vts[e*8]) = z4;  // 48*104/8
  for (int e=tid; e<832; e+=256) *reinterpret_cast<uint4*>(&Ps[e*8]) = z4;   // 64*104/8
  __syncthreads();
  for (int e=tid; e<320; e+=256){               // Q: 64 rows x 5 seg
    int row=e/5, seg=(e%5)*8;
    *reinterpret_cast<uint4*>(&Qs[row*LP+seg]) =
      *reinterpret_cast<const uint4*>(Q + ((size_t)b*kN + q0 + row)*kC + hh*kDH + seg);
  }
  for (int e=tid; e<385; e+=256){               // K: 77 rows x 5 seg
    int row=e/5, seg=(e%5)*8;
    *reinterpret_cast<uint4*>(&Ks[row*LP+seg]) =
      *reinterpret_cast<const uint4*>(KV + ((size_t)b*kLC + row)*640 + hh*kDH + seg);
  }
  for (int e=tid; e<400; e+=256){               // Vt: 40 rows(d) x 10 seg(80 tok)
    int d=e/10, seg=(e%10)*8;
    *reinterpret_cast<uint4*>(&Vts[d*LP2+seg]) =
      *reinterpret_cast<const uint4*>(Vt2 + ((size_t)b*320 + hh*kDH + d)*80 + seg);
  }
  __syncthreads();
  const f32x4 zf = {0.f,0.f,0.f,0.f};
  f32x4 sacc[5] = {zf, zf, zf, zf, zf};
  bf16x8 aq0 = *reinterpret_cast<const bf16x8*>(&Qs[(wm+lr)*LP + quad*8]);
  bf16x8 aq1 = *reinterpret_cast<const bf16x8*>(&Qs[(wm+lr)*LP + 32 + quad*8]);
  #pragma unroll
  for (int j=0;j<5;j++){
    bf16x8 bk0 = *reinterpret_cast<const bf16x8*>(&Ks[(j*16+lr)*LP + quad*8]);
    sacc[j] = __builtin_amdgcn_mfma_f32_16x16x32_bf16(aq0, bk0, sacc[j], 0,0,0);
    bf16x8 bk1 = *reinterpret_cast<const bf16x8*>(&Ks[(j*16+lr)*LP + 32 + quad*8]);
    sacc[j] = __builtin_amdgcn_mfma_f32_16x16x32_bf16(aq1, bk1, sacc[j], 0,0,0);
  }
  float l_i[4];
  #pragma unroll
  for (int r=0;r<4;r++){
    float vv[5];
    float rm = -1e30f;
    #pragma unroll
    for (int j=0;j<5;j++){
      int c = j*16 + lr;
      vv[j] = sacc[j][r]*scale;
      if (c < kLC) rm = fmaxf(rm, vv[j]);
    }
    #pragma unroll
    for (int off=1; off<16; off<<=1) rm = fmaxf(rm, __shfl_xor(rm, off, 64));
    float psum = 0.f;
    int row = wm + quad*4 + r;
    #pragma unroll
    for (int j=0;j<5;j++){
      int c = j*16 + lr;
      float p = (c < kLC) ? __expf(vv[j]-rm) : 0.f;
      psum += p;
      Ps[row*LP2 + c] = f2b(p);
    }
    #pragma unroll
    for (int off=1; off<16; off<<=1) psum += __shfl_xor(psum, off, 64);
    l_i[r] = psum;
  }
  f32x4 oacc[3] = {zf, zf, zf};
  #pragma unroll
  for (int s=0;s<3;s++){
    bf16x8 ap = *reinterpret_cast<const bf16x8*>(&Ps[(wm+lr)*LP2 + s*32 + quad*8]);
    #pragma unroll
    for (int nt=0;nt<3;nt++){
      bf16x8 bv = *reinterpret_cast<const bf16x8*>(&Vts[(nt*16+lr)*LP2 + s*32 + quad*8]);
      oacc[nt] = __builtin_amdgcn_mfma_f32_16x16x32_bf16(ap, bv, oacc[nt], 0,0,0);
    }
  }
  #pragma unroll
  for (int r=0;r<4;r++){
    float inv = 1.0f / l_i[r];
    unsigned short* Ob = Oa + ((size_t)b*kN + q0 + wm + quad*4 + r)*kC + hh*kDH;
    #pragma unroll
    for (int nt=0;nt<3;nt++){
      int d = nt*16 + lr;
      if (d < kDH) Ob[d] = f2b(oacc[nt][r]*inv);
    }
  }
}

// ---------------- unmerge + residual ----------------
__global__ void k_unmerge(const float* __restrict__ net, const float* __restrict__ Xo,
                          const int* __restrict__ merged, const int* __restrict__ node_idx,
                          const int* __restrict__ slot_of, float* __restrict__ net1){
  int blk = blockIdx.x; int b = blk >> 12; int t = blk & 4095;
  int h = t>>6, w = t&63;
  int row;
  if (!((h|w)&1)) row = kNB + ((h>>1)*32 + (w>>1));
  else {
    int i = d_arank(h,w);
    row = merged[(size_t)b*kNA+i] ? (kNB + node_idx[(size_t)b*kNA+i]) : slot_of[(size_t)b*kNA+i];
  }
  const float* np_ = net + ((size_t)b*kN + t)*kC;
  const float* xp = Xo + ((size_t)b*kNM + row)*kC;
  float* op = net1 + ((size_t)b*kN + t)*kC;
  int lane = threadIdx.x;
  #pragma unroll
  for (int q=0;q<5;q++){ int c = lane+q*64; op[c] = np_[c] + xp[c]; }
}

// ---------------- launch ----------------
extern "C" void kernel_launch(void* const* d_in, const int* in_sizes, int n_in,
                              void* d_out, int out_size, void* d_ws, size_t ws_size,
                              hipStream_t stream){
  const float* net = (const float*)d_in[0];
  const float* ctx = (const float*)d_in[1];
  const float* ln1g=(const float*)d_in[2], *ln1b=(const float*)d_in[3];
  const float* ln2g=(const float*)d_in[4], *ln2b=(const float*)d_in[5];
  const float* ln3g=(const float*)d_in[6], *ln3b=(const float*)d_in[7];
  const float* w1q=(const float*)d_in[8],  *w1k=(const float*)d_in[9];
  const float* w1v=(const float*)d_in[10], *w1o=(const float*)d_in[11];
  const float* b1o=(const float*)d_in[12];
  const float* w2q=(const float*)d_in[13], *w2k=(const float*)d_in[14];
  const float* w2v=(const float*)d_in[15], *w2o=(const float*)d_in[16];
  const float* b2o=(const float*)d_in[17];
  const float* fw1=(const float*)d_in[18], *fb1=(const float*)d_in[19];
  const float* fw2=(const float*)d_in[20], *fb2=(const float*)d_in[21];

  char* ws = (char*)d_ws;
  float* mnA  = (float*)(ws + B_mnA);
  float* mnB  = (float*)(ws + B_mnB);
  float* y32  = (float*)(ws + B_y32);
  float* xm32 = (float*)(ws + B_xm);
  float* Xo1  = (float*)(ws + B_xo1);
  float* net1 = (float*)(ws + B_net1);
  float* net2 = (float*)(ws + B_net2);
  float* cnt  = (float*)(ws + B_cnt);
  unsigned short* Hb   = (unsigned short*)(ws + B_H);
  unsigned short* Gb   = (unsigned short*)(ws + B_G);
  unsigned short* QKb  = (unsigned short*)(ws + B_QKb);
  unsigned short* Vtg  = (unsigned short*)(ws + B_Vtg);
  unsigned short* yb   = (unsigned short*)(ws + B_yb);
  unsigned short* xmb  = (unsigned short*)(ws + B_xmb);
  unsigned short* Ao1b = (unsigned short*)(ws + B_Ao1b);
  unsigned short* Q2b  = (unsigned short*)(ws + B_Q2b);
  unsigned short* Ao2b = (unsigned short*)(ws + B_Ao2b);
  unsigned short* KV2b = (unsigned short*)(ws + B_KV2b);
  unsigned short* Vt2g = (unsigned short*)(ws + B_Vt2g);
  unsigned short* ctxb = (unsigned short*)(ws + B_ctxb);
  unsigned short* Wqkv = (unsigned short*)(ws + B_Wqkv);
  unsigned short* Wo1  = (unsigned short*)(ws + B_Wo1);
  unsigned short* Wq2  = (unsigned short*)(ws + B_Wq2);
  unsigned short* Wkv2 = (unsigned short*)(ws + B_Wkv2);
  unsigned short* Wo2  = (unsigned short*)(ws + B_Wo2);
  unsigned short* Wff1 = (unsigned short*)(ws + B_Wff1);
  unsigned short* Wff2 = (unsigned short*)(ws + B_Wff2);
  unsigned long long* pack = (unsigned long long*)(ws + B_pack);
  int* rnk  = (int*)(ws + B_rank);
  int* nidx = (int*)(ws + B_nidx); int* mrg = (int*)(ws + B_mrg); int* slot = (int*)(ws + B_slot);
  int* unml = (int*)(ws + B_unml); int* ucnt = (int*)(ws + B_ucnt); int* aidx = (int*)(ws + B_aidx);

  // --- batched weight conversion + ctx convert + Vt2 pad zero ---
  k_wt_all<<<628, 256, 0, stream>>>(w1q, w1k, w1v, w1o, w2q, w2k, w2v, w2o, fw1, fw2,
                                    Wqkv, Wo1, Wq2, Wkv2, Wo2, Wff1, Wff2, ctx, ctxb, Vt2g);

  // --- ToMe indices (exact fp32); gather absorbs idx/init/rank-zero ---
  k_gather<<<kB*kN, 64, 0, stream>>>(net, mnA, mnB, pack, ucnt, aidx, rnk);
  k_scores<<<dim3(kNA/128, kNB/64, kB), 256, 0, stream>>>(mnA, mnB, pack);
  k_rank_part  <<<dim3(kNA/256, kNA/256, kB), 256, 0, stream>>>(pack, rnk);
  k_rank_assign<<<dim3(kNA/256, kB), 256, 0, stream>>>(pack, rnk, nidx, mrg, slot, unml, ucnt);
  // --- merge(LN1(net)) ---
  k_ln<false><<<kB*kN, 64, 0, stream>>>(net, ln1g, ln1b, y32);
  k_merge_ud   <<<kB*kNB*2, 64, 0, stream>>>(y32, aidx, unml, xmb, xm32, cnt);
  k_merge_src  <<<kB*kNA, 64, 0, stream>>>(y32, aidx, mrg, nidx, xm32, cnt);
  k_merge_scale<<<kB*kNB, 64, 0, stream>>>(xm32, cnt, xmb);
  // --- attn1 (self, merged seq): QKV gemm writes Q|K rows + V transposed ---
  k_bgemm64<unsigned short,false,false,1><<<dim3(64,15), 256, 0, stream>>>(
      xmb, Wqkv, nullptr, nullptr, QKb, Vtg, 4096, 960, 320, 640);
  k_attn1<<<dim3(kNM/64, kH, kB), 256, 0, stream>>>(QKb, Vtg, Ao1b);
  k_bgemm64<float,true,false,0><<<dim3(64,5), 256, 0, stream>>>(
      Ao1b, Wo1, b1o, nullptr, Xo1, nullptr, 4096, 320, 320, 320);
  k_unmerge<<<kB*kN, 64, 0, stream>>>(net, Xo1, mrg, nidx, slot, net1);
  // --- attn2 (cross): KV2 gemm writes K rows + V2 transposed ---
  k_ln<true><<<kB*kN, 64, 0, stream>>>(net1, ln2g, ln2b, yb);
  k_bgemm64<unsigned short,false,false,0><<<dim3(128,5), 256, 0, stream>>>(
      yb, Wq2, nullptr, nullptr, Q2b, nullptr, 8192, 320, 320, 320);
  k_bgemm<unsigned short,false,false,2><<<dim3(2,5), 256, 0, stream>>>(
      ctxb, Wkv2, nullptr, nullptr, KV2b, Vt2g, 154, 640, 768, 640);
  k_attn2m<<<dim3(kN/64, kH, kB), 256, 0, stream>>>(Q2b, KV2b, Vt2g, Ao2b);
  k_bgemm64<float,true,true,0><<<dim3(128,5), 256, 0, stream>>>(
      Ao2b, Wo2, b2o, net1, net2, nullptr, 8192, 320, 320, 320);
  // --- GEGLU FF ---
  k_ln<true><<<kB*kN, 64, 0, stream>>>(net2, ln3g, ln3b, yb);
  k_bgemm<unsigned short,true,false,0><<<dim3(64,20), 256, 0, stream>>>(
      yb, Wff1, fb1, nullptr, Hb, nullptr, 8192, 2560, 320, 2560);
  k_geglu<<<(kB*kN*160+255)/256, 256, 0, stream>>>(Hb, Gb);
  k_bgemm64<float,true,true,0><<<dim3(128,5), 256, 0, stream>>>(
      Gb, Wff2, fb2, net2, (float*)d_out, nullptr, 8192, 320, 1280, 320);
}

// Round 13
// 469.033 us; speedup vs baseline: 1.0465x; 1.0033x over previous
//
#include <hip/hip_runtime.h>

typedef __attribute__((ext_vector_type(8))) short bf16x8;
typedef __attribute__((ext_vector_type(4))) float f32x4;

// ---------------- problem constants ----------------
constexpr int kB   = 2;
constexpr int kN   = 4096;   // tokens (64x64)
constexpr int kC   = 320;    // channels
constexpr int kNA  = 3072;   // src (non-dst) tokens
constexpr int kNB  = 1024;   // dst tokens
constexpr int kNM  = 2048;   // merged seq len
constexpr int kR   = 2048;   // merged src count
constexpr int kH   = 8;
constexpr int kDH  = 40;
constexpr int kLC  = 77;
constexpr int kDC  = 768;
constexpr int kDFF = 1280;

__device__ __forceinline__ unsigned short f2b(float f){
  unsigned u = __float_as_uint(f);
  u += 0x7FFF + ((u>>16)&1);
  return (unsigned short)(u>>16);
}
__device__ __forceinline__ float b2f(unsigned short h){ return __uint_as_float(((unsigned)h)<<16); }

__device__ __forceinline__ float wave_sum(float v){
  #pragma unroll
  for (int m=32;m>=1;m>>=1) v += __shfl_xor(v, m, 64);
  return v;
}
__device__ __forceinline__ int d_arank(int h, int w){
  int base = 32*((h+1)>>1) + 64*(h>>1);
  return base + ((h&1) ? w : (w>>1));
}

// ---------------- ws layout (byte offsets) ----------------
constexpr size_t rndB(size_t x){ return (x + 255) & ~(size_t)255; }
constexpr size_t B_mnA  = 0;                                             // fp32 [2*3072*320]
constexpr size_t B_mnB  = rndB(B_mnA + (size_t)kB*kNA*kC*4);             // fp32 [2*1024*320]
constexpr size_t B_y32  = rndB(B_mnB + (size_t)kB*kNB*kC*4);             // fp32 [2*4096*320] (LN1)
constexpr size_t B_xm   = rndB(B_y32 + (size_t)kB*kN*kC*4);              // fp32 [2*2048*320]
constexpr size_t B_xo1  = rndB(B_xm  + (size_t)kB*kNM*kC*4);             // fp32 [2*2048*320]
constexpr size_t B_net1 = rndB(B_xo1 + (size_t)kB*kNM*kC*4);             // fp32 [2*4096*320]
constexpr size_t B_H    = 0;  // bf16 [8192*2560] overlays mnA..net1 (41.94 MB, all dead by then)
constexpr size_t B_net2 = rndB(B_net1 + (size_t)kB*kN*kC*4);             // fp32 [2*4096*320]
constexpr size_t B_G    = rndB(B_net2 + (size_t)kB*kN*kC*4);             // bf16 [8192*1280]
constexpr size_t B_QKb  = rndB(B_G    + (size_t)kB*kN*kDFF*2);           // bf16 [4096*640] (Q|K)
constexpr size_t B_Vtg  = rndB(B_QKb  + (size_t)kB*kNM*640*2);           // bf16 [320*4096] (V^T)
constexpr size_t B_yb   = rndB(B_Vtg  + (size_t)320*kB*kNM*2);           // bf16 [8192*320]
constexpr size_t B_xmb  = rndB(B_yb   + (size_t)kB*kN*kC*2);             // bf16 [4096*320]
constexpr size_t B_Ao1b = rndB(B_xmb  + (size_t)kB*kNM*kC*2);            // bf16 [4096*320]
constexpr size_t B_Q2b  = rndB(B_Ao1b + (size_t)kB*kNM*kC*2);            // bf16 [8192*320]
constexpr size_t B_Ao2b = rndB(B_Q2b  + (size_t)kB*kN*kC*2);             // bf16 [8192*320]
constexpr size_t B_KV2b = rndB(B_Ao2b + (size_t)kB*kN*kC*2);             // bf16 [154*640]
constexpr size_t B_Vt2g = rndB(B_KV2b + (size_t)kB*kLC*640*2);           // bf16 [2*320*80] (V2^T pad)
constexpr size_t B_ctxb = rndB(B_Vt2g + (size_t)kB*320*80*2);            // bf16 [154*768]
constexpr size_t B_Wqkv = rndB(B_ctxb + (size_t)kB*kLC*kDC*2);           // bf16 [960*320]
constexpr size_t B_Wo1  = rndB(B_Wqkv + (size_t)960*320*2);              // bf16 [320*320]
constexpr size_t B_Wq2  = rndB(B_Wo1  + (size_t)320*320*2);
constexpr size_t B_Wkv2 = rndB(B_Wq2  + (size_t)320*320*2);              // bf16 [640*768]
constexpr size_t B_Wo2  = rndB(B_Wkv2 + (size_t)640*768*2);
constexpr size_t B_Wff1 = rndB(B_Wo2  + (size_t)320*320*2);              // bf16 [2560*320]
constexpr size_t B_Wff2 = rndB(B_Wff1 + (size_t)2560*320*2);             // bf16 [320*1280]
constexpr size_t B_cnt  = rndB(B_Wff2 + (size_t)320*1280*2);             // fp32 [2*1024]
constexpr size_t B_pack = rndB(B_cnt  + (size_t)kB*kNB*4);               // u64 [2*3072]
constexpr size_t B_rank = rndB(B_pack + (size_t)kB*kNA*8);               // int [2*3072]
constexpr size_t B_nidx = rndB(B_rank + (size_t)kB*kNA*4);
constexpr size_t B_mrg  = rndB(B_nidx + (size_t)kB*kNA*4);
constexpr size_t B_slot = rndB(B_mrg  + (size_t)kB*kNA*4);
constexpr size_t B_unml = rndB(B_slot + (size_t)kB*kNA*4);
constexpr size_t B_ucnt = rndB(B_unml + (size_t)kB*kNB*4);
constexpr size_t B_aidx = rndB(B_ucnt + 64);

// ---------------- gather + (idx/init/rank-zero absorbed) ----------------
__global__ void k_gather(const float* __restrict__ net, float* __restrict__ mA, float* __restrict__ mB,
                         unsigned long long* __restrict__ pack, int* __restrict__ ucnt,
                         int* __restrict__ a_idx, int* __restrict__ rank){
  int blk = blockIdx.x; int b = blk >> 12; int t = blk & 4095;
  int lane = threadIdx.x;
  int gid = blk*64 + lane;
  if (gid < kB*kNA){ pack[gid] = 0ull; rank[gid] = 0; }
  if (gid < kB) ucnt[gid] = 0;
  if (gid < kN){
    int h = gid>>6, w = gid&63;
    if ((h|w)&1) a_idx[d_arank(h,w)] = gid;
  }
  const float* xp = net + ((size_t)b*kN + t)*kC;
  float v[5]; float s2 = 0.f;
  #pragma unroll
  for (int i=0;i<5;i++){ float f = xp[lane + i*64]; v[i]=f; s2 += f*f; }
  s2 = wave_sum(s2);
  float rn = 1.0f / sqrtf(s2);
  int h=t>>6, w=t&63;
  float* dp;
  if (!((h|w)&1)) dp = mB + ((size_t)b*kNB + ((h>>1)*32+(w>>1)))*kC;
  else            dp = mA + ((size_t)b*kNA + d_arank(h,w))*kC;
  #pragma unroll
  for (int i=0;i<5;i++) dp[lane + i*64] = v[i]*rn;
}

// ---------------- fused score GEMM (NT, exact fp32, 128x64 tile, BK=32, 8x4 microtile) + row argmax ----------------
__global__ __launch_bounds__(256) void k_scores(const float* __restrict__ mA, const float* __restrict__ mB,
                                                unsigned long long* __restrict__ pack){
  __shared__ __align__(16) float As[32][136];   // [k][m 0..127]
  __shared__ __align__(16) float Bs[32][68];    // [k][n 0..63]
  const int b = blockIdx.z;
  const int m0 = blockIdx.x*128, n0 = blockIdx.y*64;
  const int tid = threadIdx.x;
  const int mr = tid>>4, nc = tid&15;           // rows m0+mr*8.., cols n0+nc*4..
  const float* Ab = mA + (size_t)b*kNA*kC;
  const float* Bb = mB + (size_t)b*kNB*kC;
  float acc[8][4] = {};
  const int ar = tid>>1, ac16 = (tid&1)*16;     // A staging: 2 thr/row, 16 k each (4 float4)
  const int br = tid>>2, bc8 = (tid&3)*8;       // B staging: 4 thr/row, 8 k each (2 float4)
  for (int k0=0; k0<kC; k0+=32){
    __syncthreads();
    {
      #pragma unroll
      for (int s=0;s<4;s++){
        float4 a = *reinterpret_cast<const float4*>(&Ab[(size_t)(m0+ar)*kC + k0 + ac16 + s*4]);
        As[ac16+s*4+0][ar]=a.x; As[ac16+s*4+1][ar]=a.y; As[ac16+s*4+2][ar]=a.z; As[ac16+s*4+3][ar]=a.w;
      }
      #pragma unroll
      for (int s=0;s<2;s++){
        float4 v = *reinterpret_cast<const float4*>(&Bb[(size_t)(n0+br)*kC + k0 + bc8 + s*4]);
        Bs[bc8+s*4+0][br]=v.x; Bs[bc8+s*4+1][br]=v.y; Bs[bc8+s*4+2][br]=v.z; Bs[bc8+s*4+3][br]=v.w;
      }
    }
    __syncthreads();
    #pragma unroll
    for (int kk=0;kk<32;kk++){
      const float4 a4a = *reinterpret_cast<const float4*>(&As[kk][mr*8]);
      const float4 a4b = *reinterpret_cast<const float4*>(&As[kk][mr*8+4]);
      const float4 b4  = *reinterpret_cast<const float4*>(&Bs[kk][nc*4]);
      const float aa[8]={a4a.x,a4a.y,a4a.z,a4a.w,a4b.x,a4b.y,a4b.z,a4b.w};
      const float bb[4]={b4.x,b4.y,b4.z,b4.w};
      #pragma unroll
      for (int i=0;i<8;i++)
        #pragma unroll
        for (int j=0;j<4;j++)
          acc[i][j] = fmaf(aa[i], bb[j], acc[i][j]);
    }
  }
  #pragma unroll
  for (int i=0;i<8;i++){
    float bs = acc[i][0]; int bj = n0 + nc*4;
    #pragma unroll
    for (int j=1;j<4;j++){
      float v = acc[i][j];
      if (v > bs){ bs=v; bj=n0+nc*4+j; }
    }
    #pragma unroll
    for (int off=1; off<16; off<<=1){
      float os = __shfl_xor(bs, off, 16);
      int   oj = __shfl_xor(bj, off, 16);
      if (os > bs || (os == bs && oj < bj)){ bs=os; bj=oj; }
    }
    if (nc == 0){
      unsigned int u = __float_as_uint(bs);
      unsigned int key = (u & 0x80000000u) ? ~u : (u | 0x80000000u);
      unsigned long long pk = ((unsigned long long)key << 32) |
                              (unsigned long long)(0xFFFFFFFFu - (unsigned int)bj);
      atomicMax(&pack[(size_t)b*kNA + m0 + mr*8 + i], pk);
    }
  }
}
// partial rank over a 256-key j-chunk (grid: 12 i-blocks x 12 j-chunks x 2 batches)
__global__ __launch_bounds__(256) void k_rank_part(const unsigned long long* __restrict__ pack,
                                                   int* __restrict__ rank){
  __shared__ unsigned int keys[256];
  const int b = blockIdx.z;
  const int i = blockIdx.x*256 + threadIdx.x;
  const int j0 = blockIdx.y*256;
  const unsigned long long* pb = pack + (size_t)b*kNA;
  keys[threadIdx.x] = (unsigned int)(pb[j0 + threadIdx.x]>>32);
  unsigned int ki = (unsigned int)(pb[i]>>32);
  __syncthreads();
  int cnt = 0;
  #pragma unroll 8
  for (int jj=0;jj<256;jj++){
    unsigned int kj = keys[jj];
    int j = j0 + jj;
    cnt += (kj > ki) || (kj == ki && j < i);
  }
  atomicAdd(&rank[(size_t)b*kNA + i], cnt);
}
// decode node_idx + merged/slot assignment from accumulated rank
__global__ void k_rank_assign(const unsigned long long* __restrict__ pack, const int* __restrict__ rank,
                              int* __restrict__ node_idx, int* __restrict__ merged,
                              int* __restrict__ slot_of, int* __restrict__ unm_list,
                              int* __restrict__ ucnt){
  int b = blockIdx.y;
  int i = blockIdx.x*256 + threadIdx.x;
  unsigned long long p = pack[(size_t)b*kNA + i];
  node_idx[(size_t)b*kNA + i] = (int)(0xFFFFFFFFu - (unsigned int)(p & 0xFFFFFFFFull));
  int mg = rank[(size_t)b*kNA + i] < kR;
  merged[(size_t)b*kNA + i] = mg;
  if (!mg){
    int s = atomicAdd(&ucnt[b], 1);
    unm_list[(size_t)b*kNB + s] = i;
    slot_of[(size_t)b*kNA + i] = s;
  }
}

// ---------------- layernorm (OB: bf16 out) ----------------
template<bool OB>
__global__ void k_ln(const float* __restrict__ x, const float* __restrict__ g,
                     const float* __restrict__ be, void* __restrict__ yv){
  const int row = blockIdx.x;
  const int lane = threadIdx.x;
  const float* xp = x + (size_t)row*kC;
  float v[5]; float s=0.f, s2=0.f;
  #pragma unroll
  for (int i=0;i<5;i++){ float f = xp[lane + i*64]; v[i]=f; s+=f; s2+=f*f; }
  s = wave_sum(s); s2 = wave_sum(s2);
  float mu = s * (1.0f/kC);
  float var = s2 * (1.0f/kC) - mu*mu;
  float rstd = rsqrtf(var + 1e-5f);
  #pragma unroll
  for (int i=0;i<5;i++){
    int c = lane + i*64;
    float o = (v[i]-mu)*rstd*g[c] + be[c];
    if (OB) ((unsigned short*)yv)[(size_t)row*kC + c] = f2b(o);
    else    ((float*)yv)[(size_t)row*kC + c] = o;
  }
}

// ---------------- merge (unm + dst fused; src; scale) ----------------
__global__ void k_merge_ud(const float* __restrict__ y, const int* __restrict__ a_idx,
                           const int* __restrict__ unm_list, unsigned short* __restrict__ xmb,
                           float* __restrict__ xm, float* __restrict__ cnt){
  int blk = blockIdx.x;
  int lane = threadIdx.x;
  if (blk < kB*kNB){
    int b = blk >> 10; int s = blk & 1023;
    int i = unm_list[(size_t)b*kNB + s];
    int t = a_idx[i];
    const float* sp = y + ((size_t)b*kN + t)*kC;
    unsigned short* dp = xmb + ((size_t)b*kNM + s)*kC;
    #pragma unroll
    for (int q=0;q<5;q++) dp[lane+q*64] = f2b(sp[lane+q*64]);
  } else {
    blk -= kB*kNB;
    int b = blk >> 10; int j = blk & 1023;
    int t = 128*(j>>5) + 2*(j&31);
    const float* sp = y + ((size_t)b*kN + t)*kC;
    float* dp = xm + ((size_t)b*kNM + kNB + j)*kC;
    #pragma unroll
    for (int q=0;q<5;q++) dp[lane+q*64] = sp[lane+q*64];
    if (lane==0) cnt[(size_t)b*kNB + j] = 1.0f;
  }
}
__global__ void k_merge_src(const float* __restrict__ y, const int* __restrict__ a_idx,
                            const int* __restrict__ merged, const int* __restrict__ node_idx,
                            float* __restrict__ xm, float* __restrict__ cnt){
  int blk = blockIdx.x; int b = blk / kNA; int i = blk % kNA;
  if (!merged[(size_t)b*kNA + i]) return;
  int t = a_idx[i]; int j = node_idx[(size_t)b*kNA + i];
  const float* sp = y + ((size_t)b*kN + t)*kC;
  float* dp = xm + ((size_t)b*kNM + kNB + j)*kC;
  int lane = threadIdx.x;
  #pragma unroll
  for (int q=0;q<5;q++) atomicAdd(&dp[lane+q*64], sp[lane+q*64]);
  if (lane==0) atomicAdd(&cnt[(size_t)b*kNB + j], 1.0f);
}
__global__ void k_merge_scale(const float* __restrict__ xm, const float* __restrict__ cnt,
                              unsigned short* __restrict__ xmb){
  int blk = blockIdx.x; int b = blk >> 10; int j = blk & 1023;
  float inv = 1.0f / cnt[(size_t)b*kNB + j];
  const float* sp = xm + ((size_t)b*kNM + kNB + j)*kC;
  unsigned short* dp = xmb + ((size_t)b*kNM + kNB + j)*kC;
  int lane = threadIdx.x;
  #pragma unroll
  for (int q=0;q<5;q++) dp[lane+q*64] = f2b(sp[lane+q*64]*inv);
}

// ---------------- batched weight transpose+convert + ctx convert + Vt2 pad zero ----------------
__global__ __launch_bounds__(256) void k_wt_all(
    const float* __restrict__ w0, const float* __restrict__ w1, const float* __restrict__ w2,
    const float* __restrict__ w3, const float* __restrict__ w4, const float* __restrict__ w5,
    const float* __restrict__ w6, const float* __restrict__ w7, const float* __restrict__ w8,
    const float* __restrict__ w9,
    unsigned short* __restrict__ Wqkv, unsigned short* __restrict__ Wo1,
    unsigned short* __restrict__ Wq2,  unsigned short* __restrict__ Wkv2,
    unsigned short* __restrict__ Wo2,  unsigned short* __restrict__ Wff1,
    unsigned short* __restrict__ Wff2,
    const float* __restrict__ ctx, unsigned short* __restrict__ ctxb,
    unsigned short* __restrict__ Vt2){
  const int bid = blockIdx.x;
  const int tid = threadIdx.x;
  if (bid >= 570){
    int base = (bid-570)*2048 + tid*8;
    #pragma unroll
    for (int j=0;j<8;j++){
      int i = base + j;
      if (i < kB*kLC*kDC) ctxb[i] = f2b(ctx[i]);
    }
    if (bid == 570){
      for (int r=tid; r<kB*320; r+=256){
        Vt2[(size_t)r*80 + 77] = 0; Vt2[(size_t)r*80 + 78] = 0; Vt2[(size_t)r*80 + 79] = 0;
      }
    }
    return;
  }
  const int jb[11]   = {0,25,50,75,100,125,185,245,270,470,570};
  const float* srcs[10] = {w0,w1,w2,w3,w4,w5,w6,w7,w8,w9};
  unsigned short* dsts[10] = {Wqkv, Wqkv+320*320, Wqkv+640*320, Wo1, Wq2,
                              Wkv2, Wkv2+320*768, Wo2, Wff1, Wff2};
  const int Kd[10] = {320,320,320,320,320,768,768,320,320,1280};
  const int Nd[10] = {320,320,320,320,320,320,320,320,2560,320};
  int job = 0;
  while (bid >= jb[job+1]) job++;
  int local = bid - jb[job];
  const int Nt = (Nd[job]+63)>>6;
  int k0 = (local / Nt)*64, n0 = (local % Nt)*64;
  const float* W = srcs[job];
  unsigned short* Wt = dsts[job];
  const int K = Kd[job], N = Nd[job];
  __shared__ float tile[64][65];
  #pragma unroll
  for (int l=0;l<16;l++){
    int e = tid + l*256; int r = e>>6, c = e&63;
    int gk = k0+r, gn = n0+c;
    tile[r][c] = (gk<K && gn<N) ? W[(size_t)gk*N+gn] : 0.f;
  }
  __syncthreads();
  #pragma unroll
  for (int l=0;l<16;l++){
    int e = tid + l*256; int r = e>>6, c = e&63;
    int gn = n0+r, gk = k0+c;
    if (gn<N && gk<K) Wt[(size_t)gn*K+gk] = f2b(tile[c][r]);
  }
}

// ---------------- bf16 MFMA GEMM 128x128: out = A @ Bt^T (+bias)(+resid) ----------------
template<typename OT, bool BIAS, bool RES, int SVM>
__global__ __launch_bounds__(256) void k_bgemm(const unsigned short* __restrict__ A,
    const unsigned short* __restrict__ Bt, const float* __restrict__ bias,
    const float* __restrict__ resid, OT* __restrict__ out, unsigned short* __restrict__ vt,
    int M, int N, int K, int ldo){
  constexpr int LDK = 72;
  __shared__ unsigned short As[128*LDK];
  __shared__ unsigned short Bs[128*LDK];
  const int tid = threadIdx.x;
  const int m0 = blockIdx.x*128, n0 = blockIdx.y*128;
  const int wid = tid>>6, lane = tid&63;
  const int wm = (wid>>1)*64, wn = (wid&1)*64;
  const int lr = lane&15, quad = lane>>4;
  const f32x4 zero4 = {0.f,0.f,0.f,0.f};
  f32x4 acc[4][4];
  #pragma unroll
  for (int i=0;i<4;i++)
    #pragma unroll
    for (int j=0;j<4;j++) acc[i][j] = zero4;
  for (int k0=0; k0<K; k0+=64){
    __syncthreads();
    #pragma unroll
    for (int l=0;l<4;l++){
      int e = tid + l*256;
      int row = e>>3, seg = (e&7)*8;
      int gm = m0+row;
      uint4 va = (gm<M) ? *reinterpret_cast<const uint4*>(&A[(size_t)gm*K + k0 + seg])
                        : make_uint4(0u,0u,0u,0u);
      *reinterpret_cast<uint4*>(&As[row*LDK + seg]) = va;
      int gn = n0+row;
      uint4 vb = (gn<N) ? *reinterpret_cast<const uint4*>(&Bt[(size_t)gn*K + k0 + seg])
                        : make_uint4(0u,0u,0u,0u);
      *reinterpret_cast<uint4*>(&Bs[row*LDK + seg]) = vb;
    }
    __syncthreads();
    #pragma unroll
    for (int kk=0; kk<64; kk+=32){
      bf16x8 af[4], bfr[4];
      #pragma unroll
      for (int i=0;i<4;i++) af[i]  = *reinterpret_cast<const bf16x8*>(&As[(wm+i*16+lr)*LDK + kk + quad*8]);
      #pragma unroll
      for (int j=0;j<4;j++) bfr[j] = *reinterpret_cast<const bf16x8*>(&Bs[(wn+j*16+lr)*LDK + kk + quad*8]);
      #pragma unroll
      for (int i=0;i<4;i++)
        #pragma unroll
        for (int j=0;j<4;j++)
          acc[i][j] = __builtin_amdgcn_mfma_f32_16x16x32_bf16(af[i], bfr[j], acc[i][j], 0, 0, 0);
    }
  }
  #pragma unroll
  for (int i=0;i<4;i++){
    #pragma unroll
    for (int j=0;j<4;j++){
      int gn = n0 + wn + j*16 + lr;
      if (gn >= N) continue;
      float bv = BIAS ? bias[gn] : 0.f;
      #pragma unroll
      for (int r=0;r<4;r++){
        int gm = m0 + wm + i*16 + quad*4 + r;
        if (gm >= M) continue;
        float v = acc[i][j][r] + bv;
        if (RES) v += resid[(size_t)gm*ldo + gn];
        if (SVM == 1 && gn >= 640){
          vt[(size_t)(gn-640)*4096 + gm] = f2b(v);
        } else if (SVM == 2 && gn >= 320){
          int bb = gm / 77, tok = gm - bb*77;
          vt[((size_t)bb*320 + (gn-320))*80 + tok] = f2b(v);
        } else {
          if constexpr (sizeof(OT)==2) out[(size_t)gm*ldo + gn] = (OT)f2b(v);
          else                         out[(size_t)gm*ldo + gn] = (OT)v;
        }
      }
    }
  }
}

// ---------------- bf16 MFMA GEMM 64x64 tile (high-occupancy, for narrow-N GEMMs) ----------------
template<typename OT, bool BIAS, bool RES, int SVM>
__global__ __launch_bounds__(256) void k_bgemm64(const unsigned short* __restrict__ A,
    const unsigned short* __restrict__ Bt, const float* __restrict__ bias,
    const float* __restrict__ resid, OT* __restrict__ out, unsigned short* __restrict__ vt,
    int M, int N, int K, int ldo){
  constexpr int LDK = 72;
  __shared__ unsigned short As[64*LDK];
  __shared__ unsigned short Bs[64*LDK];
  const int tid = threadIdx.x;
  const int m0 = blockIdx.x*64, n0 = blockIdx.y*64;
  const int wid = tid>>6, lane = tid&63;
  const int wm = (wid>>1)*32, wn = (wid&1)*32;
  const int lr = lane&15, quad = lane>>4;
  const f32x4 zero4 = {0.f,0.f,0.f,0.f};
  f32x4 acc[2][2];
  #pragma unroll
  for (int i=0;i<2;i++)
    #pragma unroll
    for (int j=0;j<2;j++) acc[i][j] = zero4;
  for (int k0=0; k0<K; k0+=64){
    __syncthreads();
    #pragma unroll
    for (int l=0;l<2;l++){
      int e = tid + l*256;
      int row = e>>3, seg = (e&7)*8;
      int gm = m0+row;
      uint4 va = (gm<M) ? *reinterpret_cast<const uint4*>(&A[(size_t)gm*K + k0 + seg])
                        : make_uint4(0u,0u,0u,0u);
      *reinterpret_cast<uint4*>(&As[row*LDK + seg]) = va;
      int gn = n0+row;
      uint4 vb = (gn<N) ? *reinterpret_cast<const uint4*>(&Bt[(size_t)gn*K + k0 + seg])
                        : make_uint4(0u,0u,0u,0u);
      *reinterpret_cast<uint4*>(&Bs[row*LDK + seg]) = vb;
    }
    __syncthreads();
    #pragma unroll
    for (int kk=0; kk<64; kk+=32){
      bf16x8 af[2], bfr[2];
      #pragma unroll
      for (int i=0;i<2;i++) af[i]  = *reinterpret_cast<const bf16x8*>(&As[(wm+i*16+lr)*LDK + kk + quad*8]);
      #pragma unroll
      for (int j=0;j<2;j++) bfr[j] = *reinterpret_cast<const bf16x8*>(&Bs[(wn+j*16+lr)*LDK + kk + quad*8]);
      #pragma unroll
      for (int i=0;i<2;i++)
        #pragma unroll
        for (int j=0;j<2;j++)
          acc[i][j] = __builtin_amdgcn_mfma_f32_16x16x32_bf16(af[i], bfr[j], acc[i][j], 0, 0, 0);
    }
  }
  #pragma unroll
  for (int i=0;i<2;i++){
    #pragma unroll
    for (int j=0;j<2;j++){
      int gn = n0 + wn + j*16 + lr;
      if (gn >= N) continue;
      float bv = BIAS ? bias[gn] : 0.f;
      #pragma unroll
      for (int r=0;r<4;r++){
        int gm = m0 + wm + i*16 + quad*4 + r;
        if (gm >= M) continue;
        float v = acc[i][j][r] + bv;
        if (RES) v += resid[(size_t)gm*ldo + gn];
        if (SVM == 1 && gn >= 640){
          vt[(size_t)(gn-640)*4096 + gm] = f2b(v);
        } else if (SVM == 2 && gn >= 320){
          int bb = gm / 77, tok = gm - bb*77;
          vt[((size_t)bb*320 + (gn-320))*80 + tok] = f2b(v);
        } else {
          if constexpr (sizeof(OT)==2) out[(size_t)gm*ldo + gn] = (OT)f2b(v);
          else                         out[(size_t)gm*ldo + gn] = (OT)v;
        }
      }
    }
  }
}

// ---------------- GEGLU elementwise: G = H[:, :1280] * gelu(H[:, 1280:]) ----------------
__global__ void k_geglu(const unsigned short* __restrict__ H, unsigned short* __restrict__ G){
  int e = blockIdx.x*256 + threadIdx.x;   // 8192*160 threads
  int m = e/160, t = e - m*160;
  const unsigned short* hp = H + (size_t)m*2560 + t*8;
  uint4 xv = *reinterpret_cast<const uint4*>(hp);
  uint4 gv = *reinterpret_cast<const uint4*>(hp + 1280);
  const unsigned short* xu = reinterpret_cast<const unsigned short*>(&xv);
  const unsigned short* gu = reinterpret_cast<const unsigned short*>(&gv);
  unsigned short ov[8];
  #pragma unroll
  for (int d=0; d<8; d++){
    float x = b2f(xu[d]);
    float g = b2f(gu[d]);
    float ge = 0.5f*g*(1.0f + erff(g*0.70710678118654752f));
    ov[d] = f2b(x*ge);
  }
  *reinterpret_cast<uint4*>(G + (size_t)m*1280 + t*8) = *reinterpret_cast<const uint4*>(ov);
}

// ---------------- MFMA flash self-attn (single-pass, reg-Q, shift-free softmax) ----------------
__global__ __launch_bounds__(256) void k_attn1(const unsigned short* __restrict__ QK,
                                               const unsigned short* __restrict__ Vtg,
                                               unsigned short* __restrict__ Oa){
  constexpr int LP = 72, LV = 136;
  __shared__ unsigned short Ks[128*LP];   // [key][d pad64]
  __shared__ unsigned short Vt[48*LV];    // [d pad48][key 128 pad136]
  __shared__ unsigned short Ps[64*LV];    // [q][key 128 pad136]
  const int b = blockIdx.z, hh = blockIdx.y;
  const int q0 = blockIdx.x*64;
  const int tid = threadIdx.x;
  const int wid = tid>>6, lane = tid&63;
  const int lr = lane&15, quad = lane>>4;
  const int wm = wid*16;
  const float scale = 0.15811388300841898f; // 1/sqrt(40)
  const unsigned short* Kb = QK + ((size_t)b*kNM)*640 + 320 + hh*kDH;
  const unsigned short* Vb = Vtg + (size_t)hh*kDH*4096 + (size_t)b*kNM;
  const uint4 z4 = make_uint4(0u,0u,0u,0u);
  // Q fragments: direct per-lane 16B global loads (A-layout). Cols 40.. are pad -> zero.
  const unsigned short* Qrow = QK + ((size_t)b*kNM + q0 + wm + lr)*640 + hh*kDH;
  bf16x8 aq0 = *reinterpret_cast<const bf16x8*>(Qrow + quad*8);
  bf16x8 aq1 = {0,0,0,0,0,0,0,0};
  if (quad == 0) aq1 = *reinterpret_cast<const bf16x8*>(Qrow + 32);
  // zero pads: Ks cols 40..63 (128 x 3 segs), Vt rows 40..47 (8 x 17 segs)
  for (int e=tid; e<384; e+=256){
    int row=e/3, seg=40+(e%3)*8;
    *reinterpret_cast<uint4*>(&Ks[row*LP+seg]) = z4;
  }
  for (int e=tid; e<136; e+=256){
    int row=40+e/17, seg=(e%17)*8;
    *reinterpret_cast<uint4*>(&Vt[row*LV+seg]) = z4;
  }
  const f32x4 zf = {0.f,0.f,0.f,0.f};
  f32x4 oacc[3] = {zf, zf, zf};
  float l_i[4] = {0.f, 0.f, 0.f, 0.f};
  for (int kt=0; kt<kNM; kt+=128){
    __syncthreads();
    for (int e=tid; e<640; e+=256){          // K: 128 rows x 5 segs
      int row=e/5, seg=(e%5)*8;
      *reinterpret_cast<uint4*>(&Ks[row*LP+seg]) =
        *reinterpret_cast<const uint4*>(Kb + (size_t)(kt+row)*640 + seg);
    }
    for (int e=tid; e<640; e+=256){          // Vt: 40 d-rows x 16 segs (128 tokens)
      int d=e>>4, seg=(e&15)*8;
      *reinterpret_cast<uint4*>(&Vt[d*LV+seg]) =
        *reinterpret_cast<const uint4*>(Vb + (size_t)d*4096 + kt + seg);
    }
    __syncthreads();
    f32x4 sacc[8];
    #pragma unroll
    for (int j=0;j<8;j++){
      bf16x8 bk0 = *reinterpret_cast<const bf16x8*>(&Ks[(j*16+lr)*LP + quad*8]);
      sacc[j] = __builtin_amdgcn_mfma_f32_16x16x32_bf16(aq0, bk0, zf, 0,0,0);
      bf16x8 bk1 = *reinterpret_cast<const bf16x8*>(&Ks[(j*16+lr)*LP + 32 + quad*8]);
      sacc[j] = __builtin_amdgcn_mfma_f32_16x16x32_bf16(aq1, bk1, sacc[j], 0,0,0);
    }
    #pragma unroll
    for (int r=0;r<4;r++){
      int row = wm + quad*4 + r;
      float psum = 0.f;
      #pragma unroll
      for (int j=0;j<8;j++){
        float p = __expf(sacc[j][r]*scale);
        psum += p;
        Ps[row*LV + j*16 + lr] = f2b(p);
      }
      #pragma unroll
      for (int off=1; off<16; off<<=1) psum += __shfl_xor(psum, off, 64);
      l_i[r] += psum;
    }
    #pragma unroll
    for (int s=0;s<4;s++){
      bf16x8 ap = *reinterpret_cast<const bf16x8*>(&Ps[(wm+lr)*LV + s*32 + quad*8]);
      #pragma unroll
      for (int nt=0;nt<3;nt++){
        bf16x8 bv = *reinterpret_cast<const bf16x8*>(&Vt[(nt*16+lr)*LV + s*32 + quad*8]);
        oacc[nt] = __builtin_amdgcn_mfma_f32_16x16x32_bf16(ap, bv, oacc[nt], 0,0,0);
      }
    }
  }
  // epilogue: O[m][d], m = wm+quad*4+r, d = nt*16+lr (d<40)
  #pragma unroll
  for (int r=0;r<4;r++){
    float inv = 1.0f / l_i[r];
    unsigned short* Ob = Oa + ((size_t)b*kNM + q0 + wm + quad*4 + r)*kC + hh*kDH;
    #pragma unroll
    for (int nt=0;nt<3;nt++){
      int d = nt*16 + lr;
      if (d < kDH) Ob[d] = f2b(oacc[nt][r]*inv);
    }
  }
}

// ---------------- MFMA one-shot cross-attn: 64 q/block, 77 keys pad 80 ----------------
__global__ __launch_bounds__(256) void k_attn2m(const unsigned short* __restrict__ Q,
                                                const unsigned short* __restrict__ KV,
                                                const unsigned short* __restrict__ Vt2,
                                                unsigned short* __restrict__ Oa){
  constexpr int LP = 72, LP2 = 104;
  __shared__ unsigned short Qs[64*LP];    // [q][d pad64]
  __shared__ unsigned short Ks[80*LP];    // [key pad80][d pad64]
  __shared__ unsigned short Vts[48*LP2];  // [d pad48][key pad96]
  __shared__ unsigned short Ps[64*LP2];   // [q][key pad96]
  const int b = blockIdx.z, hh = blockIdx.y;
  const int q0 = blockIdx.x*64;
  const int tid = threadIdx.x;
  const int wid = tid>>6, lane = tid&63;
  const int lr = lane&15, quad = lane>>4;
  const int wm = wid*16;
  const float scale = 0.15811388300841898f;
  const uint4 z4 = make_uint4(0u,0u,0u,0u);
  for (int e=tid; e<576; e+=256) *reinterpret_cast<uint4*>(&Qs[e*8]) = z4;   // 64*72/8
  for (int e=tid; e<720; e+=256) *reinterpret_cast<uint4*>(&Ks[e*8]) = z4;   // 80*72/8
  for (int e=tid; e<624; e+=256) *reinterpret_cast<uint4*>(&Vts[e*8]) = z4;  // 48*104/8
  for (int e=tid; e<832; e+=256) *reinterpret_cast<uint4*>(&Ps[e*8]) = z4;   // 64*104/8
  __syncthreads();
  for (int e=tid; e<320; e+=256){               // Q: 64 rows x 5 seg
    int row=e/5, seg=(e%5)*8;
    *reinterpret_cast<uint4*>(&Qs[row*LP+seg]) =
      *reinterpret_cast<const uint4*>(Q + ((size_t)b*kN + q0 + row)*kC + hh*kDH + seg);
  }
  for (int e=tid; e<385; e+=256){               // K: 77 rows x 5 seg
    int row=e/5, seg=(e%5)*8;
    *reinterpret_cast<uint4*>(&Ks[row*LP+seg]) =
      *reinterpret_cast<const uint4*>(KV + ((size_t)b*kLC + row)*640 + hh*kDH + seg);
  }
  for (int e=tid; e<400; e+=256){               // Vt: 40 rows(d) x 10 seg(80 tok)
    int d=e/10, seg=(e%10)*8;
    *reinterpret_cast<uint4*>(&Vts[d*LP2+seg]) =
      *reinterpret_cast<const uint4*>(Vt2 + ((size_t)b*320 + hh*kDH + d)*80 + seg);
  }
  __syncthreads();
  const f32x4 zf = {0.f,0.f,0.f,0.f};
  f32x4 sacc[5] = {zf, zf, zf, zf, zf};
  bf16x8 aq0 = *reinterpret_cast<const bf16x8*>(&Qs[(wm+lr)*LP + quad*8]);
  bf16x8 aq1 = *reinterpret_cast<const bf16x8*>(&Qs[(wm+lr)*LP + 32 + quad*8]);
  #pragma unroll
  for (int j=0;j<5;j++){
    bf16x8 bk0 = *reinterpret_cast<const bf16x8*>(&Ks[(j*16+lr)*LP + quad*8]);
    sacc[j] = __builtin_amdgcn_mfma_f32_16x16x32_bf16(aq0, bk0, sacc[j], 0,0,0);
    bf16x8 bk1 = *reinterpret_cast<const bf16x8*>(&Ks[(j*16+lr)*LP + 32 + quad*8]);
    sacc[j] = __builtin_amdgcn_mfma_f32_16x16x32_bf16(aq1, bk1, sacc[j], 0,0,0);
  }
  float l_i[4];
  #pragma unroll
  for (int r=0;r<4;r++){
    float vv[5];
    float rm = -1e30f;
    #pragma unroll
    for (int j=0;j<5;j++){
      int c = j*16 + lr;
      vv[j] = sacc[j][r]*scale;
      if (c < kLC) rm = fmaxf(rm, vv[j]);
    }
    #pragma unroll
    for (int off=1; off<16; off<<=1) rm = fmaxf(rm, __shfl_xor(rm, off, 64));
    float psum = 0.f;
    int row = wm + quad*4 + r;
    #pragma unroll
    for (int j=0;j<5;j++){
      int c = j*16 + lr;
      float p = (c < kLC) ? __expf(vv[j]-rm) : 0.f;
      psum += p;
      Ps[row*LP2 + c] = f2b(p);
    }
    #pragma unroll
    for (int off=1; off<16; off<<=1) psum += __shfl_xor(psum, off, 64);
    l_i[r] = psum;
  }
  f32x4 oacc[3] = {zf, zf, zf};
  #pragma unroll
  for (int s=0;s<3;s++){
    bf16x8 ap = *reinterpret_cast<const bf16x8*>(&Ps[(wm+lr)*LP2 + s*32 + quad*8]);
    #pragma unroll
    for (int nt=0;nt<3;nt++){
      bf16x8 bv = *reinterpret_cast<const bf16x8*>(&Vts[(nt*16+lr)*LP2 + s*32 + quad*8]);
      oacc[nt] = __builtin_amdgcn_mfma_f32_16x16x32_bf16(ap, bv, oacc[nt], 0,0,0);
    }
  }
  #pragma unroll
  for (int r=0;r<4;r++){
    float inv = 1.0f / l_i[r];
    unsigned short* Ob = Oa + ((size_t)b*kN + q0 + wm + quad*4 + r)*kC + hh*kDH;
    #pragma unroll
    for (int nt=0;nt<3;nt++){
      int d = nt*16 + lr;
      if (d < kDH) Ob[d] = f2b(oacc[nt][r]*inv);
    }
  }
}

// ---------------- unmerge + residual ----------------
__global__ void k_unmerge(const float* __restrict__ net, const float* __restrict__ Xo,
                          const int* __restrict__ merged, const int* __restrict__ node_idx,
                          const int* __restrict__ slot_of, float* __restrict__ net1){
  int blk = blockIdx.x; int b = blk >> 12; int t = blk & 4095;
  int h = t>>6, w = t&63;
  int row;
  if (!((h|w)&1)) row = kNB + ((h>>1)*32 + (w>>1));
  else {
    int i = d_arank(h,w);
    row = merged[(size_t)b*kNA+i] ? (kNB + node_idx[(size_t)b*kNA+i]) : slot_of[(size_t)b*kNA+i];
  }
  const float* np_ = net + ((size_t)b*kN + t)*kC;
  const float* xp = Xo + ((size_t)b*kNM + row)*kC;
  float* op = net1 + ((size_t)b*kN + t)*kC;
  int lane = threadIdx.x;
  #pragma unroll
  for (int q=0;q<5;q++){ int c = lane+q*64; op[c] = np_[c] + xp[c]; }
}

// ---------------- launch ----------------
extern "C" void kernel_launch(void* const* d_in, const int* in_sizes, int n_in,
                              void* d_out, int out_size, void* d_ws, size_t ws_size,
                              hipStream_t stream){
  const float* net = (const float*)d_in[0];
  const float* ctx = (const float*)d_in[1];
  const float* ln1g=(const float*)d_in[2], *ln1b=(const float*)d_in[3];
  const float* ln2g=(const float*)d_in[4], *ln2b=(const float*)d_in[5];
  const float* ln3g=(const float*)d_in[6], *ln3b=(const float*)d_in[7];
  const float* w1q=(const float*)d_in[8],  *w1k=(const float*)d_in[9];
  const float* w1v=(const float*)d_in[10], *w1o=(const float*)d_in[11];
  const float* b1o=(const float*)d_in[12];
  const float* w2q=(const float*)d_in[13], *w2k=(const float*)d_in[14];
  const float* w2v=(const float*)d_in[15], *w2o=(const float*)d_in[16];
  const float* b2o=(const float*)d_in[17];
  const float* fw1=(const float*)d_in[18], *fb1=(const float*)d_in[19];
  const float* fw2=(const float*)d_in[20], *fb2=(const float*)d_in[21];

  char* ws = (char*)d_ws;
  float* mnA  = (float*)(ws + B_mnA);
  float* mnB  = (float*)(ws + B_mnB);
  float* y32  = (float*)(ws + B_y32);
  float* xm32 = (float*)(ws + B_xm);
  float* Xo1  = (float*)(ws + B_xo1);
  float* net1 = (float*)(ws + B_net1);
  float* net2 = (float*)(ws + B_net2);
  float* cnt  = (float*)(ws + B_cnt);
  unsigned short* Hb   = (unsigned short*)(ws + B_H);
  unsigned short* Gb   = (unsigned short*)(ws + B_G);
  unsigned short* QKb  = (unsigned short*)(ws + B_QKb);
  unsigned short* Vtg  = (unsigned short*)(ws + B_Vtg);
  unsigned short* yb   = (unsigned short*)(ws + B_yb);
  unsigned short* xmb  = (unsigned short*)(ws + B_xmb);
  unsigned short* Ao1b = (unsigned short*)(ws + B_Ao1b);
  unsigned short* Q2b  = (unsigned short*)(ws + B_Q2b);
  unsigned short* Ao2b = (unsigned short*)(ws + B_Ao2b);
  unsigned short* KV2b = (unsigned short*)(ws + B_KV2b);
  unsigned short* Vt2g = (unsigned short*)(ws + B_Vt2g);
  unsigned short* ctxb = (unsigned short*)(ws + B_ctxb);
  unsigned short* Wqkv = (unsigned short*)(ws + B_Wqkv);
  unsigned short* Wo1  = (unsigned short*)(ws + B_Wo1);
  unsigned short* Wq2  = (unsigned short*)(ws + B_Wq2);
  unsigned short* Wkv2 = (unsigned short*)(ws + B_Wkv2);
  unsigned short* Wo2  = (unsigned short*)(ws + B_Wo2);
  unsigned short* Wff1 = (unsigned short*)(ws + B_Wff1);
  unsigned short* Wff2 = (unsigned short*)(ws + B_Wff2);
  unsigned long long* pack = (unsigned long long*)(ws + B_pack);
  int* rnk  = (int*)(ws + B_rank);
  int* nidx = (int*)(ws + B_nidx); int* mrg = (int*)(ws + B_mrg); int* slot = (int*)(ws + B_slot);
  int* unml = (int*)(ws + B_unml); int* ucnt = (int*)(ws + B_ucnt); int* aidx = (int*)(ws + B_aidx);

  // --- batched weight conversion + ctx convert + Vt2 pad zero ---
  k_wt_all<<<628, 256, 0, stream>>>(w1q, w1k, w1v, w1o, w2q, w2k, w2v, w2o, fw1, fw2,
                                    Wqkv, Wo1, Wq2, Wkv2, Wo2, Wff1, Wff2, ctx, ctxb, Vt2g);

  // --- ToMe indices (exact fp32); gather absorbs idx/init/rank-zero ---
  k_gather<<<kB*kN, 64, 0, stream>>>(net, mnA, mnB, pack, ucnt, aidx, rnk);
  k_scores<<<dim3(kNA/128, kNB/64, kB), 256, 0, stream>>>(mnA, mnB, pack);
  k_rank_part  <<<dim3(kNA/256, kNA/256, kB), 256, 0, stream>>>(pack, rnk);
  k_rank_assign<<<dim3(kNA/256, kB), 256, 0, stream>>>(pack, rnk, nidx, mrg, slot, unml, ucnt);
  // --- merge(LN1(net)) ---
  k_ln<false><<<kB*kN, 64, 0, stream>>>(net, ln1g, ln1b, y32);
  k_merge_ud   <<<kB*kNB*2, 64, 0, stream>>>(y32, aidx, unml, xmb, xm32, cnt);
  k_merge_src  <<<kB*kNA, 64, 0, stream>>>(y32, aidx, mrg, nidx, xm32, cnt);
  k_merge_scale<<<kB*kNB, 64, 0, stream>>>(xm32, cnt, xmb);
  // --- attn1 (self, merged seq): QKV gemm writes Q|K rows + V transposed ---
  k_bgemm64<unsigned short,false,false,1><<<dim3(64,15), 256, 0, stream>>>(
      xmb, Wqkv, nullptr, nullptr, QKb, Vtg, 4096, 960, 320, 640);
  k_attn1<<<dim3(kNM/64, kH, kB), 256, 0, stream>>>(QKb, Vtg, Ao1b);
  k_bgemm64<float,true,false,0><<<dim3(64,5), 256, 0, stream>>>(
      Ao1b, Wo1, b1o, nullptr, Xo1, nullptr, 4096, 320, 320, 320);
  k_unmerge<<<kB*kN, 64, 0, stream>>>(net, Xo1, mrg, nidx, slot, net1);
  // --- attn2 (cross): KV2 gemm writes K rows + V2 transposed ---
  k_ln<true><<<kB*kN, 64, 0, stream>>>(net1, ln2g, ln2b, yb);
  k_bgemm64<unsigned short,false,false,0><<<dim3(128,5), 256, 0, stream>>>(
      yb, Wq2, nullptr, nullptr, Q2b, nullptr, 8192, 320, 320, 320);
  k_bgemm<unsigned short,false,false,2><<<dim3(2,5), 256, 0, stream>>>(
      ctxb, Wkv2, nullptr, nullptr, KV2b, Vt2g, 154, 640, 768, 640);
  k_attn2m<<<dim3(kN/64, kH, kB), 256, 0, stream>>>(Q2b, KV2b, Vt2g, Ao2b);
  k_bgemm64<float,true,true,0><<<dim3(128,5), 256, 0, stream>>>(
      Ao2b, Wo2, b2o, net1, net2, nullptr, 8192, 320, 320, 320);
  // --- GEGLU FF ---
  k_ln<true><<<kB*kN, 64, 0, stream>>>(net2, ln3g, ln3b, yb);
  k_bgemm<unsigned short,true,false,0><<<dim3(64,20), 256, 0, stream>>>(
      yb, Wff1, fb1, nullptr, Hb, nullptr, 8192, 2560, 320, 2560);
  k_geglu<<<(kB*kN*160+255)/256, 256, 0, stream>>>(Hb, Gb);
  k_bgemm64<float,true,true,0><<<dim3(128,5), 256, 0, stream>>>(
      Gb, Wff2, fb2, net2, (float*)d_out, nullptr, 8192, 320, 1280, 320);
}